// Round 2
// baseline (1590.821 us; speedup 1.0000x reference)
//
#include <hip/hip_runtime.h>
#include <hip/hip_bf16.h>

#define N_NODES 50000
#define N_EDGES 300000
#define HID 256
#define LSTR 260   // padded LDS row stride in floats
#define TN 32
#define TE 32

typedef unsigned int uint;
typedef unsigned short ushort;

__device__ __forceinline__ float bf2f(ushort u){ union{uint i; float f;} v; v.i=((uint)u)<<16; return v.f; }
__device__ __forceinline__ ushort f2bf(float f){ __hip_bfloat16 h=__float2bfloat16(f); return *reinterpret_cast<ushort*>(&h); }

__device__ __forceinline__ void fma4(float4& acc, const float4 a, const float4* w){
    acc.x += a.x*w[0].x + a.y*w[1].x + a.z*w[2].x + a.w*w[3].x;
    acc.y += a.x*w[0].y + a.y*w[1].y + a.z*w[2].y + a.w*w[3].y;
    acc.z += a.x*w[0].z + a.y*w[1].z + a.z*w[2].z + a.w*w[3].z;
    acc.w += a.x*w[0].w + a.y*w[1].w + a.z*w[2].w + a.w*w[3].w;
}

// ---------------- combined weights: W_A = sW2@gW1[256:512], W_B = sW2@gW1[512:768], W_E = eW2@gW1[0:256]
__global__ void combine_weights(const float* __restrict__ sW2, const float* __restrict__ sb2,
                                const float* __restrict__ eW2, const float* __restrict__ eb2,
                                const float* __restrict__ gW1, const float* __restrict__ gb1,
                                float* __restrict__ W_A, float* __restrict__ W_B, float* __restrict__ W_E,
                                float* __restrict__ bias_A, float* __restrict__ bias_B, float* __restrict__ bias_E)
{
    const int j = threadIdx.x;
    const int i = blockIdx.x;   // 0..256 (256 = bias row)
    const int m = blockIdx.y;   // 0:A 1:B 2:E
    const float* L  = (m==2)? eW2 : sW2;
    const float* lb = (m==2)? eb2 : sb2;
    const float* R  = gW1 + (m==0 ? HID*HID : (m==1 ? 2*HID*HID : 0));
    float acc = 0.f;
    if (i < HID){
        for (int k=0;k<HID;k++) acc += L[i*HID+k]*R[k*HID+j];
        (m==0?W_A:(m==1?W_B:W_E))[i*HID+j] = acc;
    } else {
        for (int k=0;k<HID;k++) acc += lb[k]*R[k*HID+j];
        if (m==2) acc += gb1[j];
        (m==0?bias_A:(m==1?bias_B:bias_E))[j] = acc;
    }
}

// ---------------- node encoder: gA/gB (bf16) + h0 = x_d (bf16)
__global__ __launch_bounds__(256) void node_encode(
    const float* __restrict__ sfeat, const float* __restrict__ dfeat,
    const float* __restrict__ sW1, const float* __restrict__ sb1,
    const float* __restrict__ dW1, const float* __restrict__ db1,
    const float* __restrict__ dW2, const float* __restrict__ db2,
    const float* __restrict__ W_A, const float* __restrict__ bias_A,
    const float* __restrict__ W_B, const float* __restrict__ bias_B,
    ushort* __restrict__ gA, ushort* __restrict__ gB, ushort* __restrict__ h0)
{
    __shared__ float lin[TN*LSTR];
    __shared__ float fb[TN*12];
    const int tid = threadIdx.x;
    const int n0 = blockIdx.x * TN;

    for (int i=tid; i<TN*10; i+=256){
        int n=i/10, k=i-n*10; int gn=n0+n;
        fb[n*12+k] = (gn<N_NODES)? sfeat[gn*10+k] : 0.f;
    }
    __syncthreads();
    {   const int j=tid;
        float w[10];
        #pragma unroll
        for (int k=0;k<10;k++) w[k]=sW1[k*HID+j];
        const float b=sb1[j];
        for (int n=0;n<TN;n++){
            float a=b;
            #pragma unroll
            for (int k=0;k<10;k++) a += fb[n*12+k]*w[k];
            lin[n*LSTR+j]=fmaxf(a,0.f);
        }
    }
    __syncthreads();
    const int rg=tid>>6, c0=(tid&63)*4;
    {   // gA = lin@W_A + bias_A ; gB = lin@W_B + bias_B
        float4 accA[8], accB[8];
        #pragma unroll
        for (int r=0;r<8;r++){ accA[r]=make_float4(0,0,0,0); accB[r]=make_float4(0,0,0,0); }
        for (int k=0;k<HID;k+=4){
            float4 wa[4], wb[4];
            #pragma unroll
            for (int d=0;d<4;d++){
                wa[d]=*(const float4*)&W_A[(k+d)*HID+c0];
                wb[d]=*(const float4*)&W_B[(k+d)*HID+c0];
            }
            #pragma unroll
            for (int r=0;r<8;r++){
                float4 a=*(const float4*)&lin[(rg*8+r)*LSTR+k];
                fma4(accA[r], a, wa);
                fma4(accB[r], a, wb);
            }
        }
        const float4 ba=*(const float4*)&bias_A[c0];
        const float4 bb=*(const float4*)&bias_B[c0];
        #pragma unroll
        for (int r=0;r<8;r++){
            int gn=n0+rg*8+r;
            if (gn<N_NODES){
                ushort4 ua; ua.x=f2bf(accA[r].x+ba.x); ua.y=f2bf(accA[r].y+ba.y);
                            ua.z=f2bf(accA[r].z+ba.z); ua.w=f2bf(accA[r].w+ba.w);
                ushort4 ub; ub.x=f2bf(accB[r].x+bb.x); ub.y=f2bf(accB[r].y+bb.y);
                            ub.z=f2bf(accB[r].z+bb.z); ub.w=f2bf(accB[r].w+bb.w);
                *(ushort4*)&gA[(size_t)gn*HID+c0]=ua;
                *(ushort4*)&gB[(size_t)gn*HID+c0]=ub;
            }
        }
    }
    __syncthreads();
    for (int i=tid; i<TN*12; i+=256){
        fb[i] = (n0*12+i < N_NODES*12)? dfeat[(size_t)n0*12+i] : 0.f;
    }
    __syncthreads();
    {   const int j=tid;
        float w[12];
        #pragma unroll
        for (int k=0;k<12;k++) w[k]=dW1[k*HID+j];
        const float b=db1[j];
        for (int n=0;n<TN;n++){
            float a=b;
            #pragma unroll
            for (int k=0;k<12;k++) a += fb[n*12+k]*w[k];
            lin[n*LSTR+j]=fmaxf(a,0.f);
        }
    }
    __syncthreads();
    {   // h0 = lin@dW2 + db2  (bf16 out)
        float4 acc[8];
        #pragma unroll
        for (int r=0;r<8;r++) acc[r]=make_float4(0,0,0,0);
        for (int k=0;k<HID;k+=4){
            float4 w[4];
            #pragma unroll
            for (int d=0;d<4;d++) w[d]=*(const float4*)&dW2[(k+d)*HID+c0];
            #pragma unroll
            for (int r=0;r<8;r++){
                float4 a=*(const float4*)&lin[(rg*8+r)*LSTR+k];
                fma4(acc[r], a, w);
            }
        }
        const float4 bo=*(const float4*)&db2[c0];
        #pragma unroll
        for (int r=0;r<8;r++){
            int gn=n0+rg*8+r;
            if (gn<N_NODES){
                ushort4 u; u.x=f2bf(acc[r].x+bo.x); u.y=f2bf(acc[r].y+bo.y);
                           u.z=f2bf(acc[r].z+bo.z); u.w=f2bf(acc[r].w+bo.w);
                *(ushort4*)&h0[(size_t)gn*HID+c0]=u;
            }
        }
    }
}

// ---------------- edge encoder: g (bf16, stored in CSR slot order)
__global__ __launch_bounds__(256) void edge_encode(
    const float* __restrict__ eattr, const int* __restrict__ eidx,
    const int* __restrict__ perm,
    const float* __restrict__ eW1, const float* __restrict__ eb1,
    const float* __restrict__ W_E, const float* __restrict__ bias_E,
    const float* __restrict__ gW2, const float* __restrict__ gb2,
    const ushort* __restrict__ gA, const ushort* __restrict__ gB,
    ushort* __restrict__ g_out)
{
    __shared__ float lin[TE*LSTR];
    __shared__ float eb[TE*3];
    __shared__ int si[TE], di[TE], pi[TE];
    const int tid=threadIdx.x;
    const int e0=blockIdx.x*TE;
    if (tid<TE*3) eb[tid]=eattr[(size_t)e0*3+tid];
    if (tid>=128 && tid<128+TE) si[tid-128]=eidx[e0+(tid-128)];
    if (tid>=160 && tid<160+TE) di[tid-160]=eidx[N_EDGES+e0+(tid-160)];
    if (tid>=192 && tid<192+TE) pi[tid-192]=perm[e0+(tid-192)];
    __syncthreads();
    {   const int j=tid;
        const float w0=eW1[j], w1=eW1[HID+j], w2=eW1[2*HID+j], b=eb1[j];
        for (int n=0;n<TE;n++)
            lin[n*LSTR+j]=fmaxf(b + eb[n*3]*w0 + eb[n*3+1]*w1 + eb[n*3+2]*w2, 0.f);
    }
    __syncthreads();
    const int rg=tid>>6, c0=(tid&63)*4;
    float4 acc[8];
    #pragma unroll
    for (int r=0;r<8;r++) acc[r]=make_float4(0,0,0,0);
    for (int k=0;k<HID;k+=4){
        float4 w[4];
        #pragma unroll
        for (int d=0;d<4;d++) w[d]=*(const float4*)&W_E[(k+d)*HID+c0];
        #pragma unroll
        for (int r=0;r<8;r++){
            float4 a=*(const float4*)&lin[(rg*8+r)*LSTR+k];
            fma4(acc[r], a, w);
        }
    }
    const float4 be=*(const float4*)&bias_E[c0];
    #pragma unroll
    for (int r=0;r<8;r++){
        int n=rg*8+r;
        ushort4 a4=*(const ushort4*)&gA[(size_t)si[n]*HID+c0];
        ushort4 b4=*(const ushort4*)&gB[(size_t)di[n]*HID+c0];
        acc[r].x=fmaxf(acc[r].x+bf2f(a4.x)+bf2f(b4.x)+be.x, 0.f);
        acc[r].y=fmaxf(acc[r].y+bf2f(a4.y)+bf2f(b4.y)+be.y, 0.f);
        acc[r].z=fmaxf(acc[r].z+bf2f(a4.z)+bf2f(b4.z)+be.z, 0.f);
        acc[r].w=fmaxf(acc[r].w+bf2f(a4.w)+bf2f(b4.w)+be.w, 0.f);
    }
    __syncthreads();
    #pragma unroll
    for (int r=0;r<8;r++) *(float4*)&lin[(rg*8+r)*LSTR+c0]=acc[r];
    __syncthreads();
    {   // g = lin@gW2 + gb2
        float4 a2[8];
        #pragma unroll
        for (int r=0;r<8;r++) a2[r]=make_float4(0,0,0,0);
        for (int k=0;k<HID;k+=4){
            float4 w[4];
            #pragma unroll
            for (int d=0;d<4;d++) w[d]=*(const float4*)&gW2[(k+d)*HID+c0];
            #pragma unroll
            for (int r=0;r<8;r++){
                float4 a=*(const float4*)&lin[(rg*8+r)*LSTR+k];
                fma4(a2[r], a, w);
            }
        }
        const float4 bg=*(const float4*)&gb2[c0];
        #pragma unroll
        for (int r=0;r<8;r++){
            int n=rg*8+r;
            ushort4 u; u.x=f2bf(a2[r].x+bg.x); u.y=f2bf(a2[r].y+bg.y);
                       u.z=f2bf(a2[r].z+bg.z); u.w=f2bf(a2[r].w+bg.w);
            *(ushort4*)&g_out[(size_t)pi[n]*HID+c0]=u;
        }
    }
}

// ---------------- CSR build
__global__ void deg_count(const int* __restrict__ eidx, uint* __restrict__ deg){
    int e=blockIdx.x*blockDim.x+threadIdx.x;
    if (e<N_EDGES) atomicAdd(&deg[eidx[N_EDGES+e]],1u);
}

__global__ void scan_kernel(const uint* __restrict__ deg, uint* __restrict__ row_start){
    __shared__ uint wtot[16];
    __shared__ uint woff[17];
    __shared__ uint carry_s;
    const int tid=threadIdx.x, lane=tid&63, wid=tid>>6;
    if (tid==0) carry_s=0;
    __syncthreads();
    for (uint base=0; base<N_NODES; base+=1024){
        uint idx=base+tid;
        uint v=(idx<N_NODES)? deg[idx]:0u;
        uint s=v;
        #pragma unroll
        for (int d=1; d<64; d<<=1){
            uint t=__shfl_up(s,d,64);
            if (lane>=d) s+=t;
        }
        if (lane==63) wtot[wid]=s;
        __syncthreads();
        if (tid==0){ uint r=0; for (int i=0;i<16;i++){ woff[i]=r; r+=wtot[i]; } woff[16]=r; }
        __syncthreads();
        uint excl = carry_s + woff[wid] + s - v;
        if (idx<N_NODES) row_start[idx]=excl;
        __syncthreads();
        if (tid==0) carry_s += woff[16];
        __syncthreads();
    }
}

__global__ void csr_fill(const int* __restrict__ eidx, const uint* __restrict__ row_start,
                         uint* __restrict__ cursor, int* __restrict__ csr_src, int* __restrict__ perm){
    int e=blockIdx.x*blockDim.x+threadIdx.x;
    if (e>=N_EDGES) return;
    int d=eidx[N_EDGES+e];
    uint pos=atomicAdd(&cursor[d],1u);
    uint s=row_start[d]+pos;
    csr_src[s]=eidx[e];
    perm[e]=(int)s;
}

// ---------------- message-passing hop: one wave per node, CSR gather, bf16 h in/out
__global__ __launch_bounds__(256) void hop_kernel(
    const ushort* __restrict__ h_in, ushort* __restrict__ h_out,
    const ushort* __restrict__ g, const int* __restrict__ csr_src,
    const uint* __restrict__ row_start, const uint* __restrict__ deg)
{
    const int gw=(blockIdx.x*blockDim.x+threadIdx.x)>>6;
    if (gw>=N_NODES) return;
    const int c0=(threadIdx.x&63)*4;
    ushort4 hd4=*(const ushort4*)&h_in[(size_t)gw*HID+c0];
    float4 hd; hd.x=bf2f(hd4.x); hd.y=bf2f(hd4.y); hd.z=bf2f(hd4.z); hd.w=bf2f(hd4.w);
    float4 acc=make_float4(0,0,0,0);
    const uint st=row_start[gw], len=deg[gw];
    for (uint u=0;u<len;u++){
        uint s=st+u;
        int sn=csr_src[s];
        ushort4 g4=*(const ushort4*)&g[(size_t)s*HID+c0];
        ushort4 hs4=*(const ushort4*)&h_in[(size_t)sn*HID+c0];
        acc.x += bf2f(g4.x)*(bf2f(hs4.x)-hd.x);
        acc.y += bf2f(g4.y)*(bf2f(hs4.y)-hd.y);
        acc.z += bf2f(g4.z)*(bf2f(hs4.z)-hd.z);
        acc.w += bf2f(g4.w)*(bf2f(hs4.w)-hd.w);
    }
    const float inv=1.f/fmaxf((float)len,1.f);
    ushort4 o; o.x=f2bf(hd.x+acc.x*inv); o.y=f2bf(hd.y+acc.y*inv);
               o.z=f2bf(hd.z+acc.z*inv); o.w=f2bf(hd.w+acc.w*inv);
    *(ushort4*)&h_out[(size_t)gw*HID+c0]=o;
}

// ---------------- decoder: out = relu(tanh(h)@oW1+ob1)@oW2+ob2   (h is bf16)
__global__ __launch_bounds__(256) void decoder(
    const ushort* __restrict__ h,
    const float* __restrict__ oW1, const float* __restrict__ ob1,
    const float* __restrict__ oW2, const float* __restrict__ ob2,
    float* __restrict__ out)
{
    __shared__ float xr[TN*LSTR];
    const int tid=threadIdx.x;
    const int n0=blockIdx.x*TN;
    for (int i=tid;i<TN*64;i+=256){
        int n=i>>6, c=(i&63)*4;
        float4 t=make_float4(0,0,0,0);
        if (n0+n<N_NODES){
            ushort4 v=*(const ushort4*)&h[(size_t)(n0+n)*HID+c];
            t.x=tanhf(bf2f(v.x)); t.y=tanhf(bf2f(v.y)); t.z=tanhf(bf2f(v.z)); t.w=tanhf(bf2f(v.w));
        }
        *(float4*)&xr[n*LSTR+c]=t;
    }
    __syncthreads();
    const int rg=tid>>6, c0=(tid&63)*4;
    float4 acc[8];
    #pragma unroll
    for (int r=0;r<8;r++) acc[r]=make_float4(0,0,0,0);
    for (int k=0;k<HID;k+=4){
        float4 w[4];
        #pragma unroll
        for (int d=0;d<4;d++) w[d]=*(const float4*)&oW1[(k+d)*HID+c0];
        #pragma unroll
        for (int r=0;r<8;r++){
            float4 a=*(const float4*)&xr[(rg*8+r)*LSTR+k];
            fma4(acc[r], a, w);
        }
    }
    const float4 bo=*(const float4*)&ob1[c0];
    __syncthreads();
    #pragma unroll
    for (int r=0;r<8;r++){
        float4 v=acc[r];
        v.x=fmaxf(v.x+bo.x,0.f); v.y=fmaxf(v.y+bo.y,0.f);
        v.z=fmaxf(v.z+bo.z,0.f); v.w=fmaxf(v.w+bo.w,0.f);
        *(float4*)&xr[(rg*8+r)*LSTR+c0]=v;
    }
    __syncthreads();
    if (tid<TN*3){
        int n=tid/3, o=tid-n*3;
        float a=ob2[o];
        for (int k=0;k<HID;k++) a += xr[n*LSTR+k]*oW2[k*3+o];
        if (n0+n<N_NODES) out[(size_t)(n0+n)*3+o]=a;
    }
}

extern "C" void kernel_launch(void* const* d_in, const int* in_sizes, int n_in,
                              void* d_out, int out_size, void* d_ws, size_t ws_size,
                              hipStream_t stream)
{
    (void)in_sizes; (void)n_in; (void)out_size;
    const float* sfeat=(const float*)d_in[0];
    const float* dfeat=(const float*)d_in[1];
    const int*   eidx =(const int*)  d_in[2];
    const float* eattr=(const float*)d_in[3];
    const float* sW1=(const float*)d_in[4];  const float* sb1=(const float*)d_in[5];
    const float* sW2=(const float*)d_in[6];  const float* sb2=(const float*)d_in[7];
    const float* dW1=(const float*)d_in[8];  const float* db1=(const float*)d_in[9];
    const float* dW2=(const float*)d_in[10]; const float* db2=(const float*)d_in[11];
    const float* eW1=(const float*)d_in[12]; const float* eb1=(const float*)d_in[13];
    const float* eW2=(const float*)d_in[14]; const float* eb2=(const float*)d_in[15];
    const float* gW1=(const float*)d_in[16]; const float* gb1=(const float*)d_in[17];
    const float* gW2=(const float*)d_in[18]; const float* gb2=(const float*)d_in[19];
    const float* oW1=(const float*)d_in[20]; const float* ob1=(const float*)d_in[21];
    const float* oW2=(const float*)d_in[22]; const float* ob2=(const float*)d_in[23];
    float* out=(float*)d_out;

    char* p=(char*)d_ws;
    size_t used=0;
    auto alloc=[&](size_t bytes)->char*{
        char* r=p+used; used += (bytes+255)&~(size_t)255; return r;
    };
    float* W_A=(float*)alloc(HID*HID*4);
    float* W_B=(float*)alloc(HID*HID*4);
    float* W_E=(float*)alloc(HID*HID*4);
    float* bias_A=(float*)alloc(HID*4);
    float* bias_B=(float*)alloc(HID*4);
    float* bias_E=(float*)alloc(HID*4);
    ushort* gA=(ushort*)alloc((size_t)N_NODES*HID*2);
    ushort* gB=(ushort*)alloc((size_t)N_NODES*HID*2);
    ushort* g =(ushort*)alloc((size_t)N_EDGES*HID*2);
    ushort* h0=(ushort*)alloc((size_t)N_NODES*HID*2);
    uint* deg      =(uint*)alloc(N_NODES*4);
    uint* row_start=(uint*)alloc(N_NODES*4);
    uint* cursor   =(uint*)alloc(N_NODES*4);
    int* csr_src=(int*)alloc(N_EDGES*4);
    int* perm   =(int*)alloc(N_EDGES*4);
    ushort* h1=gA;   // alias: gA/gB dead after edge_encode; h1 (25.6MB) fits in gA region

    // Diagnostic guard: if workspace is too small, do nothing (clean absmax fail,
    // distinguishable from a device fault).
    if (used > ws_size) return;

    hipMemsetAsync(deg, 0, N_NODES*4, stream);
    hipMemsetAsync(cursor, 0, N_NODES*4, stream);

    combine_weights<<<dim3(HID+1,3),256,0,stream>>>(sW2,sb2,eW2,eb2,gW1,gb1,W_A,W_B,W_E,bias_A,bias_B,bias_E);
    node_encode<<<(N_NODES+TN-1)/TN,256,0,stream>>>(sfeat,dfeat,sW1,sb1,dW1,db1,dW2,db2,W_A,bias_A,W_B,bias_B,gA,gB,h0);
    deg_count<<<(N_EDGES+255)/256,256,0,stream>>>(eidx,deg);
    scan_kernel<<<1,1024,0,stream>>>(deg,row_start);
    csr_fill<<<(N_EDGES+255)/256,256,0,stream>>>(eidx,row_start,cursor,csr_src,perm);
    edge_encode<<<N_EDGES/TE,256,0,stream>>>(eattr,eidx,perm,eW1,eb1,W_E,bias_E,gW2,gb2,gA,gB,g);
    hop_kernel<<<N_NODES/4,256,0,stream>>>(h0,h1,g,csr_src,row_start,deg);
    hop_kernel<<<N_NODES/4,256,0,stream>>>(h1,h0,g,csr_src,row_start,deg);
    decoder<<<(N_NODES+TN-1)/TN,256,0,stream>>>(h0,oW1,ob1,oW2,ob2,out);
}

// Round 3
// 754.875 us; speedup vs baseline: 2.1074x; 2.1074x over previous
//
#include <hip/hip_runtime.h>
#include <hip/hip_bf16.h>

#define N_NODES 50000
#define N_EDGES 300000
#define HID 256
#define AS 264      // LDS act stride in bf16 elems: 264*2=528B = 33*16 -> 16B-aligned rows, conflict-free
#define LSTR 260    // fp32 LDS stride for decoder
#define TN 32

typedef unsigned int uint;
typedef unsigned short ushort;
typedef short bf16x8 __attribute__((ext_vector_type(8)));
typedef float f32x4 __attribute__((ext_vector_type(4)));

__device__ __forceinline__ float bf2f(ushort u){ union{uint i; float f;} v; v.i=((uint)u)<<16; return v.f; }
__device__ __forceinline__ ushort f2bf(float f){ __hip_bfloat16 h=__float2bfloat16(f); return *reinterpret_cast<ushort*>(&h); }

__device__ __forceinline__ f32x4 mfma16(bf16x8 a, bf16x8 b, f32x4 c){
    return __builtin_amdgcn_mfma_f32_16x16x32_bf16(a, b, c, 0, 0, 0);
}

// wave computes rows 0..63 (A in LDS, row-major stride AS) x cols [n0,n0+64) of WT (bf16 [N][K] row-major)
__device__ __forceinline__ void wave_gemm(const ushort* act, const ushort* __restrict__ WT,
                                          int n0, int lane, f32x4 acc[4][4])
{
    #pragma unroll
    for (int mi=0;mi<4;mi++)
        #pragma unroll
        for (int ni=0;ni<4;ni++) acc[mi][ni]=(f32x4){0.f,0.f,0.f,0.f};
    const int rA=lane&15, kg=(lane>>4)*8;
    #pragma unroll
    for (int kk=0;kk<8;kk++){
        const int ka=kk*32+kg;
        bf16x8 a[4], b[4];
        #pragma unroll
        for (int mi=0;mi<4;mi++) a[mi]=*(const bf16x8*)&act[(mi*16+rA)*AS+ka];
        #pragma unroll
        for (int ni=0;ni<4;ni++) b[ni]=*(const bf16x8*)&WT[(size_t)((n0+ni*16+rA)*HID+ka)];
        #pragma unroll
        for (int mi=0;mi<4;mi++)
            #pragma unroll
            for (int ni=0;ni<4;ni++)
                acc[mi][ni]=mfma16(a[mi], b[ni], acc[mi][ni]);
    }
}

// ---------------- combined weights -> bf16 transposed: WT_A=(sW2@gW1[256:512])^T etc.
__global__ void combine_weights(const float* __restrict__ sW2, const float* __restrict__ sb2,
                                const float* __restrict__ eW2, const float* __restrict__ eb2,
                                const float* __restrict__ gW1, const float* __restrict__ gb1,
                                ushort* __restrict__ WT_A, ushort* __restrict__ WT_B, ushort* __restrict__ WT_E,
                                float* __restrict__ bias_A, float* __restrict__ bias_B, float* __restrict__ bias_E)
{
    const int j = threadIdx.x;
    const int i = blockIdx.x;   // 0..256 (256 = bias row)
    const int m = blockIdx.y;   // 0:A 1:B 2:E
    const float* L  = (m==2)? eW2 : sW2;
    const float* lb = (m==2)? eb2 : sb2;
    const float* R  = gW1 + (m==0 ? HID*HID : (m==1 ? 2*HID*HID : 0));
    float acc = 0.f;
    if (i < HID){
        for (int k=0;k<HID;k++) acc += L[i*HID+k]*R[k*HID+j];
        (m==0?WT_A:(m==1?WT_B:WT_E))[j*HID+i] = f2bf(acc);
    } else {
        for (int k=0;k<HID;k++) acc += lb[k]*R[k*HID+j];
        if (m==2) acc += gb1[j];
        (m==0?bias_A:(m==1?bias_B:bias_E))[j] = acc;
    }
}

// src [K=256][N=256] f32 -> dst [N][K] bf16
__global__ void transpose_to_bf16(const float* __restrict__ src, ushort* __restrict__ dst){
    const int k=blockIdx.x, n=threadIdx.x;
    dst[n*HID+k]=f2bf(src[k*HID+n]);
}

// ---------------- node encoder (MFMA): gA/gB (bf16) + h0 (bf16)
__global__ __launch_bounds__(256) void node_encode_mfma(
    const float* __restrict__ sfeat, const float* __restrict__ dfeat,
    const float* __restrict__ sW1, const float* __restrict__ sb1,
    const float* __restrict__ dW1, const float* __restrict__ db1,
    const ushort* __restrict__ WT_d, const float* __restrict__ db2,
    const ushort* __restrict__ WT_A, const float* __restrict__ bias_A,
    const ushort* __restrict__ WT_B, const float* __restrict__ bias_B,
    ushort* __restrict__ gA, ushort* __restrict__ gB, ushort* __restrict__ h0)
{
    __shared__ ushort act[64*AS];
    __shared__ float fb[64*12];
    const int tid=threadIdx.x;
    const int n0blk=blockIdx.x*64;
    const int wv=tid>>6, lane=tid&63, n0=wv*64;
    const int colb=n0+(lane&15);

    // stage static feats [64][10]
    for (int i=tid;i<64*10;i+=256){
        int n=i/10, k=i-n*10; int gn=n0blk+n;
        fb[n*10+k]=(gn<N_NODES)? sfeat[(size_t)gn*10+k]:0.f;
    }
    __syncthreads();
    {   // layer1 static -> act (bf16)
        const int j=tid;
        float w[10];
        #pragma unroll
        for (int k=0;k<10;k++) w[k]=sW1[k*HID+j];
        const float b=sb1[j];
        for (int n=0;n<64;n++){
            float a=b;
            #pragma unroll
            for (int k=0;k<10;k++) a+=fb[n*10+k]*w[k];
            act[n*AS+j]=f2bf(fmaxf(a,0.f));
        }
    }
    __syncthreads();
    f32x4 acc[4][4];
    {   // gA = act @ WT_A^T + bias_A
        wave_gemm(act, WT_A, n0, lane, acc);
        #pragma unroll
        for (int mi=0;mi<4;mi++){
            #pragma unroll
            for (int ni=0;ni<4;ni++){
                const int col=colb+ni*16; const float bA=bias_A[col];
                #pragma unroll
                for (int r=0;r<4;r++){
                    int rr=mi*16+(lane>>4)*4+r; int gn=n0blk+rr;
                    if (gn<N_NODES) gA[(size_t)gn*HID+col]=f2bf(acc[mi][ni][r]+bA);
                }
            }
        }
    }
    {   // gB
        wave_gemm(act, WT_B, n0, lane, acc);
        #pragma unroll
        for (int mi=0;mi<4;mi++){
            #pragma unroll
            for (int ni=0;ni<4;ni++){
                const int col=colb+ni*16; const float bB=bias_B[col];
                #pragma unroll
                for (int r=0;r<4;r++){
                    int rr=mi*16+(lane>>4)*4+r; int gn=n0blk+rr;
                    if (gn<N_NODES) gB[(size_t)gn*HID+col]=f2bf(acc[mi][ni][r]+bB);
                }
            }
        }
    }
    __syncthreads();
    // stage dynamic feats [64][12]
    for (int i=tid;i<64*12;i+=256){
        int n=i/12, k=i-n*12; int gn=n0blk+n;
        fb[n*12+k]=(gn<N_NODES)? dfeat[(size_t)gn*12+k]:0.f;
    }
    __syncthreads();
    {   // layer1 dynamic -> act
        const int j=tid;
        float w[12];
        #pragma unroll
        for (int k=0;k<12;k++) w[k]=dW1[k*HID+j];
        const float b=db1[j];
        for (int n=0;n<64;n++){
            float a=b;
            #pragma unroll
            for (int k=0;k<12;k++) a+=fb[n*12+k]*w[k];
            act[n*AS+j]=f2bf(fmaxf(a,0.f));
        }
    }
    __syncthreads();
    {   // h0 = act @ WT_d^T + db2
        wave_gemm(act, WT_d, n0, lane, acc);
        #pragma unroll
        for (int mi=0;mi<4;mi++){
            #pragma unroll
            for (int ni=0;ni<4;ni++){
                const int col=colb+ni*16; const float bo=db2[col];
                #pragma unroll
                for (int r=0;r<4;r++){
                    int rr=mi*16+(lane>>4)*4+r; int gn=n0blk+rr;
                    if (gn<N_NODES) h0[(size_t)gn*HID+col]=f2bf(acc[mi][ni][r]+bo);
                }
            }
        }
    }
}

// ---------------- edge encoder (MFMA): g (bf16, CSR slot order)
__global__ __launch_bounds__(256) void edge_encode_mfma(
    const float* __restrict__ eattr, const int* __restrict__ eidx,
    const int* __restrict__ perm,
    const float* __restrict__ eW1, const float* __restrict__ eb1,
    const ushort* __restrict__ WT_E, const float* __restrict__ bias_E,
    const ushort* __restrict__ WT_g2, const float* __restrict__ gb2,
    const ushort* __restrict__ gA, const ushort* __restrict__ gB,
    ushort* __restrict__ g_out)
{
    __shared__ ushort act[64*AS];
    __shared__ float eb[64*3];
    __shared__ int si[64], di[64], pi[64];
    const int tid=threadIdx.x;
    const int e0=blockIdx.x*64;
    const int wv=tid>>6, lane=tid&63, n0=wv*64;
    const int colb=n0+(lane&15);

    if (tid<192) eb[tid]=((size_t)e0*3+tid < (size_t)N_EDGES*3)? eattr[(size_t)e0*3+tid]:0.f;
    if (tid<64){
        int e=e0+tid; bool v=e<N_EDGES;
        si[tid]=v? eidx[e]:0; di[tid]=v? eidx[N_EDGES+e]:0; pi[tid]=v? perm[e]:0;
    }
    __syncthreads();
    {   // layer1: relu(eattr@eW1+eb1) -> act
        const int j=tid;
        const float w0=eW1[j], w1=eW1[HID+j], w2=eW1[2*HID+j], b=eb1[j];
        for (int n=0;n<64;n++)
            act[n*AS+j]=f2bf(fmaxf(b+eb[n*3]*w0+eb[n*3+1]*w1+eb[n*3+2]*w2, 0.f));
    }
    __syncthreads();
    f32x4 acc[4][4];
    wave_gemm(act, WT_E, n0, lane, acc);
    __syncthreads();   // all waves done reading act
    // epilogue1: + bias_E + gA[src] + gB[dst], relu -> act
    #pragma unroll
    for (int mi=0;mi<4;mi++){
        #pragma unroll
        for (int ni=0;ni<4;ni++){
            const int col=colb+ni*16; const float bE=bias_E[col];
            #pragma unroll
            for (int r=0;r<4;r++){
                int rr=mi*16+(lane>>4)*4+r;
                float v=acc[mi][ni][r]+bE+bf2f(gA[(size_t)si[rr]*HID+col])+bf2f(gB[(size_t)di[rr]*HID+col]);
                act[rr*AS+col]=f2bf(fmaxf(v,0.f));
            }
        }
    }
    __syncthreads();
    wave_gemm(act, WT_g2, n0, lane, acc);
    // epilogue2: + gb2 -> g_out[perm]
    #pragma unroll
    for (int mi=0;mi<4;mi++){
        #pragma unroll
        for (int ni=0;ni<4;ni++){
            const int col=colb+ni*16; const float bg=gb2[col];
            #pragma unroll
            for (int r=0;r<4;r++){
                int rr=mi*16+(lane>>4)*4+r;
                if (e0+rr<N_EDGES)
                    g_out[(size_t)pi[rr]*HID+col]=f2bf(acc[mi][ni][r]+bg);
            }
        }
    }
}

// ---------------- CSR build
__global__ void deg_count(const int* __restrict__ eidx, uint* __restrict__ deg){
    int e=blockIdx.x*blockDim.x+threadIdx.x;
    if (e<N_EDGES) atomicAdd(&deg[eidx[N_EDGES+e]],1u);
}

__global__ void scan_kernel(const uint* __restrict__ deg, uint* __restrict__ row_start){
    __shared__ uint wtot[16];
    __shared__ uint woff[17];
    __shared__ uint carry_s;
    const int tid=threadIdx.x, lane=tid&63, wid=tid>>6;
    if (tid==0) carry_s=0;
    __syncthreads();
    for (uint base=0; base<N_NODES; base+=1024){
        uint idx=base+tid;
        uint v=(idx<N_NODES)? deg[idx]:0u;
        uint s=v;
        #pragma unroll
        for (int d=1; d<64; d<<=1){
            uint t=__shfl_up(s,d,64);
            if (lane>=d) s+=t;
        }
        if (lane==63) wtot[wid]=s;
        __syncthreads();
        if (tid==0){ uint r=0; for (int i=0;i<16;i++){ woff[i]=r; r+=wtot[i]; } woff[16]=r; }
        __syncthreads();
        uint excl = carry_s + woff[wid] + s - v;
        if (idx<N_NODES) row_start[idx]=excl;
        __syncthreads();
        if (tid==0) carry_s += woff[16];
        __syncthreads();
    }
}

__global__ void csr_fill(const int* __restrict__ eidx, const uint* __restrict__ row_start,
                         uint* __restrict__ cursor, int* __restrict__ csr_src, int* __restrict__ perm){
    int e=blockIdx.x*blockDim.x+threadIdx.x;
    if (e>=N_EDGES) return;
    int d=eidx[N_EDGES+e];
    uint pos=atomicAdd(&cursor[d],1u);
    uint s=row_start[d]+pos;
    csr_src[s]=eidx[e];
    perm[e]=(int)s;
}

// ---------------- message-passing hop: one wave per node, CSR gather, bf16 h in/out
__global__ __launch_bounds__(256) void hop_kernel(
    const ushort* __restrict__ h_in, ushort* __restrict__ h_out,
    const ushort* __restrict__ g, const int* __restrict__ csr_src,
    const uint* __restrict__ row_start, const uint* __restrict__ deg)
{
    const int gw=(blockIdx.x*blockDim.x+threadIdx.x)>>6;
    if (gw>=N_NODES) return;
    const int c0=(threadIdx.x&63)*4;
    ushort4 hd4=*(const ushort4*)&h_in[(size_t)gw*HID+c0];
    float4 hd; hd.x=bf2f(hd4.x); hd.y=bf2f(hd4.y); hd.z=bf2f(hd4.z); hd.w=bf2f(hd4.w);
    float4 acc=make_float4(0,0,0,0);
    const uint st=row_start[gw], len=deg[gw];
    for (uint u=0;u<len;u++){
        uint s=st+u;
        int sn=csr_src[s];
        ushort4 g4=*(const ushort4*)&g[(size_t)s*HID+c0];
        ushort4 hs4=*(const ushort4*)&h_in[(size_t)sn*HID+c0];
        acc.x += bf2f(g4.x)*(bf2f(hs4.x)-hd.x);
        acc.y += bf2f(g4.y)*(bf2f(hs4.y)-hd.y);
        acc.z += bf2f(g4.z)*(bf2f(hs4.z)-hd.z);
        acc.w += bf2f(g4.w)*(bf2f(hs4.w)-hd.w);
    }
    const float inv=1.f/fmaxf((float)len,1.f);
    ushort4 o; o.x=f2bf(hd.x+acc.x*inv); o.y=f2bf(hd.y+acc.y*inv);
               o.z=f2bf(hd.z+acc.z*inv); o.w=f2bf(hd.w+acc.w*inv);
    *(ushort4*)&h_out[(size_t)gw*HID+c0]=o;
}

// ---------------- decoder: out = relu(tanh(h)@oW1+ob1)@oW2+ob2   (h is bf16)
__global__ __launch_bounds__(256) void decoder(
    const ushort* __restrict__ h,
    const float* __restrict__ oW1, const float* __restrict__ ob1,
    const float* __restrict__ oW2, const float* __restrict__ ob2,
    float* __restrict__ out)
{
    __shared__ float xr[TN*LSTR];
    const int tid=threadIdx.x;
    const int n0=blockIdx.x*TN;
    for (int i=tid;i<TN*64;i+=256){
        int n=i>>6, c=(i&63)*4;
        float4 t=make_float4(0,0,0,0);
        if (n0+n<N_NODES){
            ushort4 v=*(const ushort4*)&h[(size_t)(n0+n)*HID+c];
            t.x=tanhf(bf2f(v.x)); t.y=tanhf(bf2f(v.y)); t.z=tanhf(bf2f(v.z)); t.w=tanhf(bf2f(v.w));
        }
        *(float4*)&xr[n*LSTR+c]=t;
    }
    __syncthreads();
    const int rg=tid>>6, c0=(tid&63)*4;
    float4 acc[8];
    #pragma unroll
    for (int r=0;r<8;r++) acc[r]=make_float4(0,0,0,0);
    for (int k=0;k<HID;k+=4){
        float4 w[4];
        #pragma unroll
        for (int d=0;d<4;d++) w[d]=*(const float4*)&oW1[(k+d)*HID+c0];
        #pragma unroll
        for (int r=0;r<8;r++){
            const float4 a=*(const float4*)&xr[(rg*8+r)*LSTR+k];
            acc[r].x += a.x*w[0].x + a.y*w[1].x + a.z*w[2].x + a.w*w[3].x;
            acc[r].y += a.x*w[0].y + a.y*w[1].y + a.z*w[2].y + a.w*w[3].y;
            acc[r].z += a.x*w[0].z + a.y*w[1].z + a.z*w[2].z + a.w*w[3].z;
            acc[r].w += a.x*w[0].w + a.y*w[1].w + a.z*w[2].w + a.w*w[3].w;
        }
    }
    const float4 bo=*(const float4*)&ob1[c0];
    __syncthreads();
    #pragma unroll
    for (int r=0;r<8;r++){
        float4 v=acc[r];
        v.x=fmaxf(v.x+bo.x,0.f); v.y=fmaxf(v.y+bo.y,0.f);
        v.z=fmaxf(v.z+bo.z,0.f); v.w=fmaxf(v.w+bo.w,0.f);
        *(float4*)&xr[(rg*8+r)*LSTR+c0]=v;
    }
    __syncthreads();
    if (tid<TN*3){
        int n=tid/3, o=tid-n*3;
        float a=ob2[o];
        for (int k=0;k<HID;k++) a += xr[n*LSTR+k]*oW2[k*3+o];
        if (n0+n<N_NODES) out[(size_t)(n0+n)*3+o]=a;
    }
}

extern "C" void kernel_launch(void* const* d_in, const int* in_sizes, int n_in,
                              void* d_out, int out_size, void* d_ws, size_t ws_size,
                              hipStream_t stream)
{
    (void)in_sizes; (void)n_in; (void)out_size;
    const float* sfeat=(const float*)d_in[0];
    const float* dfeat=(const float*)d_in[1];
    const int*   eidx =(const int*)  d_in[2];
    const float* eattr=(const float*)d_in[3];
    const float* sW1=(const float*)d_in[4];  const float* sb1=(const float*)d_in[5];
    const float* sW2=(const float*)d_in[6];  const float* sb2=(const float*)d_in[7];
    const float* dW1=(const float*)d_in[8];  const float* db1=(const float*)d_in[9];
    const float* dW2=(const float*)d_in[10]; const float* db2=(const float*)d_in[11];
    const float* eW1=(const float*)d_in[12]; const float* eb1=(const float*)d_in[13];
    const float* eW2=(const float*)d_in[14]; const float* eb2=(const float*)d_in[15];
    const float* gW1=(const float*)d_in[16]; const float* gb1=(const float*)d_in[17];
    const float* gW2=(const float*)d_in[18]; const float* gb2=(const float*)d_in[19];
    const float* oW1=(const float*)d_in[20]; const float* ob1=(const float*)d_in[21];
    const float* oW2=(const float*)d_in[22]; const float* ob2=(const float*)d_in[23];
    float* out=(float*)d_out;

    char* p=(char*)d_ws;
    size_t used=0;
    auto alloc=[&](size_t bytes)->char*{
        char* r=p+used; used += (bytes+255)&~(size_t)255; return r;
    };
    ushort* WT_A=(ushort*)alloc(HID*HID*2);
    ushort* WT_B=(ushort*)alloc(HID*HID*2);
    ushort* WT_E=(ushort*)alloc(HID*HID*2);
    ushort* WT_d=(ushort*)alloc(HID*HID*2);
    ushort* WT_g=(ushort*)alloc(HID*HID*2);
    float* bias_A=(float*)alloc(HID*4);
    float* bias_B=(float*)alloc(HID*4);
    float* bias_E=(float*)alloc(HID*4);
    ushort* gA=(ushort*)alloc((size_t)N_NODES*HID*2);
    ushort* gB=(ushort*)alloc((size_t)N_NODES*HID*2);
    ushort* g =(ushort*)alloc((size_t)N_EDGES*HID*2);
    ushort* h0=(ushort*)alloc((size_t)N_NODES*HID*2);
    uint* deg      =(uint*)alloc(N_NODES*4);
    uint* row_start=(uint*)alloc(N_NODES*4);
    uint* cursor   =(uint*)alloc(N_NODES*4);
    int* csr_src=(int*)alloc(N_EDGES*4);
    int* perm   =(int*)alloc(N_EDGES*4);
    ushort* h1=gA;   // alias: gA/gB dead after edge_encode

    if (used > ws_size) return;  // clean fail if ws too small

    hipMemsetAsync(deg, 0, N_NODES*4, stream);
    hipMemsetAsync(cursor, 0, N_NODES*4, stream);

    combine_weights<<<dim3(HID+1,3),256,0,stream>>>(sW2,sb2,eW2,eb2,gW1,gb1,WT_A,WT_B,WT_E,bias_A,bias_B,bias_E);
    transpose_to_bf16<<<HID,HID,0,stream>>>(dW2, WT_d);
    transpose_to_bf16<<<HID,HID,0,stream>>>(gW2, WT_g);
    node_encode_mfma<<<(N_NODES+63)/64,256,0,stream>>>(sfeat,dfeat,sW1,sb1,dW1,db1,WT_d,db2,WT_A,bias_A,WT_B,bias_B,gA,gB,h0);
    deg_count<<<(N_EDGES+255)/256,256,0,stream>>>(eidx,deg);
    scan_kernel<<<1,1024,0,stream>>>(deg,row_start);
    csr_fill<<<(N_EDGES+255)/256,256,0,stream>>>(eidx,row_start,cursor,csr_src,perm);
    edge_encode_mfma<<<(N_EDGES+63)/64,256,0,stream>>>(eattr,eidx,perm,eW1,eb1,WT_E,bias_E,WT_g,gb2,gA,gB,g);
    hop_kernel<<<N_NODES/4,256,0,stream>>>(h0,h1,g,csr_src,row_start,deg);
    hop_kernel<<<N_NODES/4,256,0,stream>>>(h1,h0,g,csr_src,row_start,deg);
    decoder<<<(N_NODES+TN-1)/TN,256,0,stream>>>(h0,oW1,ob1,oW2,ob2,out);
}

// Round 4
// 710.281 us; speedup vs baseline: 2.2397x; 1.0628x over previous
//
#include <hip/hip_runtime.h>
#include <hip/hip_bf16.h>

#define N_NODES 50000
#define N_EDGES 300000
#define HID 256
#define AS 264      // LDS act stride in bf16 elems: 264*2=528B = 33*16 -> 16B-aligned rows, conflict-free
#define TN 32

typedef unsigned int uint;
typedef unsigned short ushort;
typedef short bf16x8 __attribute__((ext_vector_type(8)));
typedef unsigned short u16x8 __attribute__((ext_vector_type(8)));
typedef float f32x4 __attribute__((ext_vector_type(4)));

// LDS-only barrier: order ds ops, do NOT drain vmcnt (keeps prefetch loads in flight)
#define LDS_BAR() do{ asm volatile("s_waitcnt lgkmcnt(0)" ::: "memory"); __builtin_amdgcn_s_barrier(); }while(0)

__device__ __forceinline__ float bf2f(ushort u){ union{uint i; float f;} v; v.i=((uint)u)<<16; return v.f; }
__device__ __forceinline__ ushort f2bf(float f){ __hip_bfloat16 h=__float2bfloat16(f); return *reinterpret_cast<ushort*>(&h); }

__device__ __forceinline__ f32x4 mfma16(bf16x8 a, bf16x8 b, f32x4 c){
    return __builtin_amdgcn_mfma_f32_16x16x32_bf16(a, b, c, 0, 0, 0);
}

// wave computes rows 0..63 (A in LDS, row-major stride AS) x cols [n0,n0+64) of WT (bf16 [N][K] row-major)
__device__ __forceinline__ void wave_gemm(const ushort* act, const ushort* __restrict__ WT,
                                          int n0, int lane, f32x4 acc[4][4])
{
    #pragma unroll
    for (int mi=0;mi<4;mi++)
        #pragma unroll
        for (int ni=0;ni<4;ni++) acc[mi][ni]=(f32x4){0.f,0.f,0.f,0.f};
    const int rA=lane&15, kg=(lane>>4)*8;
    #pragma unroll
    for (int kk=0;kk<8;kk++){
        const int ka=kk*32+kg;
        bf16x8 a[4], b[4];
        #pragma unroll
        for (int mi=0;mi<4;mi++) a[mi]=*(const bf16x8*)&act[(mi*16+rA)*AS+ka];
        #pragma unroll
        for (int ni=0;ni<4;ni++) b[ni]=*(const bf16x8*)&WT[(size_t)((n0+ni*16+rA)*HID+ka)];
        #pragma unroll
        for (int mi=0;mi<4;mi++)
            #pragma unroll
            for (int ni=0;ni<4;ni++)
                acc[mi][ni]=mfma16(a[mi], b[ni], acc[mi][ni]);
    }
}

// ---------------- combined weights -> bf16 transposed  (+ plain transposes for dW2/gW2/oW1)
__global__ void combine_weights(const float* __restrict__ sW2, const float* __restrict__ sb2,
                                const float* __restrict__ eW2, const float* __restrict__ eb2,
                                const float* __restrict__ gW1, const float* __restrict__ gb1,
                                const float* __restrict__ dW2, const float* __restrict__ gW2,
                                const float* __restrict__ oW1,
                                ushort* __restrict__ WT_A, ushort* __restrict__ WT_B, ushort* __restrict__ WT_E,
                                ushort* __restrict__ WT_d, ushort* __restrict__ WT_g, ushort* __restrict__ WT_o,
                                float* __restrict__ bias_A, float* __restrict__ bias_B, float* __restrict__ bias_E)
{
    const int j = threadIdx.x;
    const int i = blockIdx.x;   // 0..256 (256 = bias row)
    const int m = blockIdx.y;   // 0:A 1:B 2:E 3:dW2 4:gW2 5:oW1
    if (m>=3){
        if (i<HID){
            const float* S = (m==3)? dW2 : (m==4)? gW2 : oW1;
            ushort* D      = (m==3)? WT_d : (m==4)? WT_g : WT_o;
            D[j*HID+i]=f2bf(S[i*HID+j]);
        }
        return;
    }
    const float* L  = (m==2)? eW2 : sW2;
    const float* lb = (m==2)? eb2 : sb2;
    const float* R  = gW1 + (m==0 ? HID*HID : (m==1 ? 2*HID*HID : 0));
    float acc = 0.f;
    if (i < HID){
        for (int k=0;k<HID;k++) acc += L[i*HID+k]*R[k*HID+j];
        (m==0?WT_A:(m==1?WT_B:WT_E))[j*HID+i] = f2bf(acc);
    } else {
        for (int k=0;k<HID;k++) acc += lb[k]*R[k*HID+j];
        if (m==2) acc += gb1[j];
        (m==0?bias_A:(m==1?bias_B:bias_E))[j] = acc;
    }
}

// ---------------- node encoder (MFMA): gA/gB (bf16) + h0 (bf16)
__global__ __launch_bounds__(256) void node_encode_mfma(
    const float* __restrict__ sfeat, const float* __restrict__ dfeat,
    const float* __restrict__ sW1, const float* __restrict__ sb1,
    const float* __restrict__ dW1, const float* __restrict__ db1,
    const ushort* __restrict__ WT_d, const float* __restrict__ db2,
    const ushort* __restrict__ WT_A, const float* __restrict__ bias_A,
    const ushort* __restrict__ WT_B, const float* __restrict__ bias_B,
    ushort* __restrict__ gA, ushort* __restrict__ gB, ushort* __restrict__ h0)
{
    __shared__ ushort act[64*AS];
    __shared__ float fb[64*12];
    const int tid=threadIdx.x;
    const int n0blk=blockIdx.x*64;
    const int wv=tid>>6, lane=tid&63, n0=wv*64;
    const int colb=n0+(lane&15);

    for (int i=tid;i<64*10;i+=256){
        int n=i/10, k=i-n*10; int gn=n0blk+n;
        fb[n*10+k]=(gn<N_NODES)? sfeat[(size_t)gn*10+k]:0.f;
    }
    __syncthreads();
    {   const int j=tid;
        float w[10];
        #pragma unroll
        for (int k=0;k<10;k++) w[k]=sW1[k*HID+j];
        const float b=sb1[j];
        for (int n=0;n<64;n++){
            float a=b;
            #pragma unroll
            for (int k=0;k<10;k++) a+=fb[n*10+k]*w[k];
            act[n*AS+j]=f2bf(fmaxf(a,0.f));
        }
    }
    __syncthreads();
    f32x4 acc[4][4];
    {   // gA = act @ WT_A^T + bias_A
        wave_gemm(act, WT_A, n0, lane, acc);
        #pragma unroll
        for (int mi=0;mi<4;mi++){
            #pragma unroll
            for (int ni=0;ni<4;ni++){
                const int col=colb+ni*16; const float bA=bias_A[col];
                #pragma unroll
                for (int r=0;r<4;r++){
                    int rr=mi*16+(lane>>4)*4+r; int gn=n0blk+rr;
                    if (gn<N_NODES) gA[(size_t)gn*HID+col]=f2bf(acc[mi][ni][r]+bA);
                }
            }
        }
    }
    {   // gB
        wave_gemm(act, WT_B, n0, lane, acc);
        #pragma unroll
        for (int mi=0;mi<4;mi++){
            #pragma unroll
            for (int ni=0;ni<4;ni++){
                const int col=colb+ni*16; const float bB=bias_B[col];
                #pragma unroll
                for (int r=0;r<4;r++){
                    int rr=mi*16+(lane>>4)*4+r; int gn=n0blk+rr;
                    if (gn<N_NODES) gB[(size_t)gn*HID+col]=f2bf(acc[mi][ni][r]+bB);
                }
            }
        }
    }
    __syncthreads();
    for (int i=tid;i<64*12;i+=256){
        int n=i/12, k=i-n*12; int gn=n0blk+n;
        fb[n*12+k]=(gn<N_NODES)? dfeat[(size_t)gn*12+k]:0.f;
    }
    __syncthreads();
    {   const int j=tid;
        float w[12];
        #pragma unroll
        for (int k=0;k<12;k++) w[k]=dW1[k*HID+j];
        const float b=db1[j];
        for (int n=0;n<64;n++){
            float a=b;
            #pragma unroll
            for (int k=0;k<12;k++) a+=fb[n*12+k]*w[k];
            act[n*AS+j]=f2bf(fmaxf(a,0.f));
        }
    }
    __syncthreads();
    {   // h0 = act @ WT_d^T + db2
        wave_gemm(act, WT_d, n0, lane, acc);
        #pragma unroll
        for (int mi=0;mi<4;mi++){
            #pragma unroll
            for (int ni=0;ni<4;ni++){
                const int col=colb+ni*16; const float bo=db2[col];
                #pragma unroll
                for (int r=0;r<4;r++){
                    int rr=mi*16+(lane>>4)*4+r; int gn=n0blk+rr;
                    if (gn<N_NODES) h0[(size_t)gn*HID+col]=f2bf(acc[mi][ni][r]+bo);
                }
            }
        }
    }
}

// ---------------- edge encoder (MFMA, CSR-slot order, prefetched gA gathers)
__global__ __launch_bounds__(256) void edge_encode_mfma(
    const float* __restrict__ eattr, const int* __restrict__ eidx,
    const int* __restrict__ csr_src, const int* __restrict__ csr_eid,
    const float* __restrict__ eW1, const float* __restrict__ eb1,
    const ushort* __restrict__ WT_E, const float* __restrict__ bias_E,
    const ushort* __restrict__ WT_g2, const float* __restrict__ gb2,
    const ushort* __restrict__ gA, const ushort* __restrict__ gB,
    ushort* __restrict__ g_out)
{
    __shared__ ushort act[64*AS];
    __shared__ float eb[64*3];
    __shared__ int si[64], di[64];
    const int tid=threadIdx.x;
    const int s0=blockIdx.x*64;
    const int wv=tid>>6, lane=tid&63, n0=wv*64;
    const int colb=n0+(lane&15);
    const int hi=lane>>4;

    if (tid<64){
        int s=s0+tid; bool v=s<N_EDGES;
        int eid=v? csr_eid[s]:0;
        si[tid]=v? csr_src[s]:0;
        di[tid]=v? eidx[N_EDGES+eid]:0;
        float a0=0.f,a1=0.f,a2=0.f;
        if (v){ a0=eattr[(size_t)eid*3]; a1=eattr[(size_t)eid*3+1]; a2=eattr[(size_t)eid*3+2]; }
        eb[tid*3]=a0; eb[tid*3+1]=a1; eb[tid*3+2]=a2;
    }
    LDS_BAR();
    // prefetch gA[src] gathers into regs NOW; consumed after gemm1 (latency hidden)
    ushort gpre[4][4][4];
    #pragma unroll
    for (int mi=0;mi<4;mi++){
        #pragma unroll
        for (int r=0;r<4;r++){
            const int row=si[mi*16+hi*4+r];
            #pragma unroll
            for (int ni=0;ni<4;ni++)
                gpre[mi][ni][r]=gA[(size_t)row*HID+colb+ni*16];
        }
    }
    {   // layer1: relu(eattr@eW1+eb1) -> act
        const int j=tid;
        const float w0=eW1[j], w1=eW1[HID+j], w2=eW1[2*HID+j], b=eb1[j];
        for (int n=0;n<64;n++)
            act[n*AS+j]=f2bf(fmaxf(b+eb[n*3]*w0+eb[n*3+1]*w1+eb[n*3+2]*w2, 0.f));
    }
    LDS_BAR();
    f32x4 acc[4][4];
    wave_gemm(act, WT_E, n0, lane, acc);
    LDS_BAR();   // all waves done reading act
    // epilogue1: + bias_E + gA(prefetched) + gB[dst] (sorted dst -> cache hits), relu -> act
    #pragma unroll
    for (int mi=0;mi<4;mi++){
        #pragma unroll
        for (int ni=0;ni<4;ni++){
            const int col=colb+ni*16; const float bE=bias_E[col];
            #pragma unroll
            for (int r=0;r<4;r++){
                const int rr=mi*16+hi*4+r;
                float vv=acc[mi][ni][r]+bE+bf2f(gpre[mi][ni][r])+bf2f(gB[(size_t)di[rr]*HID+col]);
                act[rr*AS+col]=f2bf(fmaxf(vv,0.f));
            }
        }
    }
    LDS_BAR();
    wave_gemm(act, WT_g2, n0, lane, acc);
    // epilogue2: + gb2 -> g_out[slot] (contiguous rows, coalesced)
    #pragma unroll
    for (int mi=0;mi<4;mi++){
        #pragma unroll
        for (int ni=0;ni<4;ni++){
            const int col=colb+ni*16; const float bg=gb2[col];
            #pragma unroll
            for (int r=0;r<4;r++){
                const int rr=mi*16+hi*4+r;
                if (s0+rr<N_EDGES)
                    g_out[(size_t)(s0+rr)*HID+col]=f2bf(acc[mi][ni][r]+bg);
            }
        }
    }
}

// ---------------- CSR build
__global__ void deg_count(const int* __restrict__ eidx, uint* __restrict__ deg){
    int e=blockIdx.x*blockDim.x+threadIdx.x;
    if (e<N_EDGES) atomicAdd(&deg[eidx[N_EDGES+e]],1u);
}

__global__ void scan_kernel(const uint* __restrict__ deg, uint* __restrict__ row_start){
    __shared__ uint wtot[16];
    __shared__ uint woff[17];
    __shared__ uint carry_s;
    const int tid=threadIdx.x, lane=tid&63, wid=tid>>6;
    if (tid==0) carry_s=0;
    __syncthreads();
    for (uint base=0; base<N_NODES; base+=1024){
        uint idx=base+tid;
        uint v=(idx<N_NODES)? deg[idx]:0u;
        uint s=v;
        #pragma unroll
        for (int d=1; d<64; d<<=1){
            uint t=__shfl_up(s,d,64);
            if (lane>=d) s+=t;
        }
        if (lane==63) wtot[wid]=s;
        __syncthreads();
        if (tid==0){ uint r=0; for (int i=0;i<16;i++){ woff[i]=r; r+=wtot[i]; } woff[16]=r; }
        __syncthreads();
        uint excl = carry_s + woff[wid] + s - v;
        if (idx<N_NODES) row_start[idx]=excl;
        __syncthreads();
        if (tid==0) carry_s += woff[16];
        __syncthreads();
    }
}

__global__ void csr_fill(const int* __restrict__ eidx, const uint* __restrict__ row_start,
                         uint* __restrict__ cursor, int* __restrict__ csr_src, int* __restrict__ csr_eid){
    int e=blockIdx.x*blockDim.x+threadIdx.x;
    if (e>=N_EDGES) return;
    int d=eidx[N_EDGES+e];
    uint pos=atomicAdd(&cursor[d],1u);
    uint s=row_start[d]+pos;
    csr_src[s]=eidx[e];
    csr_eid[s]=e;
}

// ---------------- message-passing hop: one wave per node, CSR gather, bf16 h in/out
__global__ __launch_bounds__(256) void hop_kernel(
    const ushort* __restrict__ h_in, ushort* __restrict__ h_out,
    const ushort* __restrict__ g, const int* __restrict__ csr_src,
    const uint* __restrict__ row_start, const uint* __restrict__ deg)
{
    const int gw=(blockIdx.x*blockDim.x+threadIdx.x)>>6;
    if (gw>=N_NODES) return;
    const int c0=(threadIdx.x&63)*4;
    ushort4 hd4=*(const ushort4*)&h_in[(size_t)gw*HID+c0];
    float4 hd; hd.x=bf2f(hd4.x); hd.y=bf2f(hd4.y); hd.z=bf2f(hd4.z); hd.w=bf2f(hd4.w);
    float4 acc=make_float4(0,0,0,0);
    const uint st=row_start[gw], len=deg[gw];
    for (uint u=0;u<len;u++){
        uint s=st+u;
        int sn=csr_src[s];
        ushort4 g4=*(const ushort4*)&g[(size_t)s*HID+c0];
        ushort4 hs4=*(const ushort4*)&h_in[(size_t)sn*HID+c0];
        acc.x += bf2f(g4.x)*(bf2f(hs4.x)-hd.x);
        acc.y += bf2f(g4.y)*(bf2f(hs4.y)-hd.y);
        acc.z += bf2f(g4.z)*(bf2f(hs4.z)-hd.z);
        acc.w += bf2f(g4.w)*(bf2f(hs4.w)-hd.w);
    }
    const float inv=1.f/fmaxf((float)len,1.f);
    ushort4 o; o.x=f2bf(hd.x+acc.x*inv); o.y=f2bf(hd.y+acc.y*inv);
               o.z=f2bf(hd.z+acc.z*inv); o.w=f2bf(hd.w+acc.w*inv);
    *(ushort4*)&h_out[(size_t)gw*HID+c0]=o;
}

// ---------------- decoder (MFMA): out = relu(tanh(h)@oW1+ob1)@oW2+ob2
__global__ __launch_bounds__(256) void decoder_mfma(
    const ushort* __restrict__ h, const ushort* __restrict__ WT_o,
    const float* __restrict__ ob1, const float* __restrict__ oW2, const float* __restrict__ ob2,
    float* __restrict__ out)
{
    __shared__ ushort act[64*AS];
    const int tid=threadIdx.x, n0blk=blockIdx.x*64;
    const int wv=tid>>6, lane=tid&63, n0=wv*64, colb=n0+(lane&15);
    {   // stage tanh(h) -> act (bf16); 4 threads per row, 64 cols each
        const int row=tid>>2, cc=(tid&3)*64;
        const int gn=n0blk+row;
        #pragma unroll
        for (int k=0;k<64;k+=8){
            u16x8 t;
            if (gn<N_NODES){
                u16x8 v=*(const u16x8*)&h[(size_t)gn*HID+cc+k];
                #pragma unroll
                for (int j=0;j<8;j++) t[j]=f2bf(tanhf(bf2f(v[j])));
            } else {
                #pragma unroll
                for (int j=0;j<8;j++) t[j]=0;
            }
            *(u16x8*)&act[row*AS+cc+k]=t;
        }
    }
    __syncthreads();
    f32x4 acc[4][4];
    wave_gemm(act, WT_o, n0, lane, acc);
    __syncthreads();
    #pragma unroll
    for (int mi=0;mi<4;mi++){
        #pragma unroll
        for (int ni=0;ni<4;ni++){
            const int col=colb+ni*16; const float b1=ob1[col];
            #pragma unroll
            for (int r=0;r<4;r++){
                const int rr=mi*16+(lane>>4)*4+r;
                act[rr*AS+col]=f2bf(fmaxf(acc[mi][ni][r]+b1,0.f));
            }
        }
    }
    __syncthreads();
    if (tid<192){
        const int n=tid/3, o=tid-n*3;
        float a=ob2[o];
        for (int k=0;k<HID;k++) a+=bf2f(act[n*AS+k])*oW2[k*3+o];
        const int gn=n0blk+n;
        if (gn<N_NODES) out[(size_t)gn*3+o]=a;
    }
}

extern "C" void kernel_launch(void* const* d_in, const int* in_sizes, int n_in,
                              void* d_out, int out_size, void* d_ws, size_t ws_size,
                              hipStream_t stream)
{
    (void)in_sizes; (void)n_in; (void)out_size;
    const float* sfeat=(const float*)d_in[0];
    const float* dfeat=(const float*)d_in[1];
    const int*   eidx =(const int*)  d_in[2];
    const float* eattr=(const float*)d_in[3];
    const float* sW1=(const float*)d_in[4];  const float* sb1=(const float*)d_in[5];
    const float* sW2=(const float*)d_in[6];  const float* sb2=(const float*)d_in[7];
    const float* dW1=(const float*)d_in[8];  const float* db1=(const float*)d_in[9];
    const float* dW2=(const float*)d_in[10]; const float* db2=(const float*)d_in[11];
    const float* eW1=(const float*)d_in[12]; const float* eb1=(const float*)d_in[13];
    const float* eW2=(const float*)d_in[14]; const float* eb2=(const float*)d_in[15];
    const float* gW1=(const float*)d_in[16]; const float* gb1=(const float*)d_in[17];
    const float* gW2=(const float*)d_in[18]; const float* gb2=(const float*)d_in[19];
    const float* oW1=(const float*)d_in[20]; const float* ob1=(const float*)d_in[21];
    const float* oW2=(const float*)d_in[22]; const float* ob2=(const float*)d_in[23];
    float* out=(float*)d_out;

    char* p=(char*)d_ws;
    size_t used=0;
    auto alloc=[&](size_t bytes)->char*{
        char* r=p+used; used += (bytes+255)&~(size_t)255; return r;
    };
    ushort* WT_A=(ushort*)alloc(HID*HID*2);
    ushort* WT_B=(ushort*)alloc(HID*HID*2);
    ushort* WT_E=(ushort*)alloc(HID*HID*2);
    ushort* WT_d=(ushort*)alloc(HID*HID*2);
    ushort* WT_g=(ushort*)alloc(HID*HID*2);
    ushort* WT_o=(ushort*)alloc(HID*HID*2);
    float* bias_A=(float*)alloc(HID*4);
    float* bias_B=(float*)alloc(HID*4);
    float* bias_E=(float*)alloc(HID*4);
    ushort* gA=(ushort*)alloc((size_t)N_NODES*HID*2);
    ushort* gB=(ushort*)alloc((size_t)N_NODES*HID*2);
    ushort* g =(ushort*)alloc((size_t)N_EDGES*HID*2);
    ushort* h0=(ushort*)alloc((size_t)N_NODES*HID*2);
    uint* deg      =(uint*)alloc(N_NODES*4);
    uint* row_start=(uint*)alloc(N_NODES*4);
    uint* cursor   =(uint*)alloc(N_NODES*4);
    int* csr_src=(int*)alloc(N_EDGES*4);
    int* csr_eid=(int*)alloc(N_EDGES*4);
    ushort* h1=gA;   // alias: gA/gB dead after edge_encode

    if (used > ws_size) return;  // clean fail if ws too small

    hipMemsetAsync(deg, 0, N_NODES*4, stream);
    hipMemsetAsync(cursor, 0, N_NODES*4, stream);

    combine_weights<<<dim3(HID+1,6),256,0,stream>>>(sW2,sb2,eW2,eb2,gW1,gb1,dW2,gW2,oW1,
                                                    WT_A,WT_B,WT_E,WT_d,WT_g,WT_o,bias_A,bias_B,bias_E);
    node_encode_mfma<<<(N_NODES+63)/64,256,0,stream>>>(sfeat,dfeat,sW1,sb1,dW1,db1,WT_d,db2,WT_A,bias_A,WT_B,bias_B,gA,gB,h0);
    deg_count<<<(N_EDGES+255)/256,256,0,stream>>>(eidx,deg);
    scan_kernel<<<1,1024,0,stream>>>(deg,row_start);
    csr_fill<<<(N_EDGES+255)/256,256,0,stream>>>(eidx,row_start,cursor,csr_src,csr_eid);
    edge_encode_mfma<<<(N_EDGES+63)/64,256,0,stream>>>(eattr,eidx,csr_src,csr_eid,eW1,eb1,WT_E,bias_E,WT_g,gb2,gA,gB,g);
    hop_kernel<<<N_NODES/4,256,0,stream>>>(h0,h1,g,csr_src,row_start,deg);
    hop_kernel<<<N_NODES/4,256,0,stream>>>(h1,h0,g,csr_src,row_start,deg);
    decoder_mfma<<<(N_NODES+63)/64,256,0,stream>>>(h0,WT_o,ob1,oW2,ob2,out);
}

// Round 5
// 653.226 us; speedup vs baseline: 2.4353x; 1.0873x over previous
//
#include <hip/hip_runtime.h>
#include <hip/hip_bf16.h>

#define N_NODES 50000
#define N_EDGES 300000
#define HID 256
#define AS 264      // LDS act stride in bf16 elems: 264*2=528B, 16B-aligned rows
#define TN 32

typedef unsigned int uint;
typedef unsigned short ushort;
typedef short bf16x8 __attribute__((ext_vector_type(8)));
typedef unsigned short u16x8 __attribute__((ext_vector_type(8)));
typedef float f32x4 __attribute__((ext_vector_type(4)));

// LDS-only barrier: order ds ops, do NOT drain vmcnt (keeps DMA loads in flight)
#define LDS_BAR() do{ asm volatile("s_waitcnt lgkmcnt(0)" ::: "memory"); __builtin_amdgcn_s_barrier(); }while(0)
// full barrier: also drain vmcnt (DMA completion)
#define FULL_BAR() do{ asm volatile("s_waitcnt vmcnt(0) lgkmcnt(0)" ::: "memory"); __builtin_amdgcn_s_barrier(); }while(0)

__device__ __forceinline__ float bf2f(ushort u){ union{uint i; float f;} v; v.i=((uint)u)<<16; return v.f; }
__device__ __forceinline__ ushort f2bf(float f){ __hip_bfloat16 h=__float2bfloat16(h==h?f:f); return *reinterpret_cast<ushort*>(&h); }

__device__ __forceinline__ f32x4 mfma16(bf16x8 a, bf16x8 b, f32x4 c){
    return __builtin_amdgcn_mfma_f32_16x16x32_bf16(a, b, c, 0, 0, 0);
}

// async global->LDS: 16B per lane, dest = lds base + lane*16
__device__ __forceinline__ void gload_lds16(const ushort* g, ushort* l){
    __builtin_amdgcn_global_load_lds(
        (const __attribute__((address_space(1))) unsigned int*)g,
        (__attribute__((address_space(3))) unsigned int*)l, 16, 0, 0);
}

// wave computes rows 0..63 (A in LDS, row-major stride AS) x cols [n0,n0+64) of WT (bf16 [N][K] row-major)
__device__ __forceinline__ void wave_gemm(const ushort* act, const ushort* __restrict__ WT,
                                          int n0, int lane, f32x4 acc[4][4])
{
    #pragma unroll
    for (int mi=0;mi<4;mi++)
        #pragma unroll
        for (int ni=0;ni<4;ni++) acc[mi][ni]=(f32x4){0.f,0.f,0.f,0.f};
    const int rA=lane&15, kg=(lane>>4)*8;
    #pragma unroll
    for (int kk=0;kk<8;kk++){
        const int ka=kk*32+kg;
        bf16x8 a[4], b[4];
        #pragma unroll
        for (int mi=0;mi<4;mi++) a[mi]=*(const bf16x8*)&act[(mi*16+rA)*AS+ka];
        #pragma unroll
        for (int ni=0;ni<4;ni++) b[ni]=*(const bf16x8*)&WT[(size_t)((n0+ni*16+rA)*HID+ka)];
        #pragma unroll
        for (int mi=0;mi<4;mi++)
            #pragma unroll
            for (int ni=0;ni<4;ni++)
                acc[mi][ni]=mfma16(a[mi], b[ni], acc[mi][ni]);
    }
}

// ---------------- combined weights -> bf16 transposed  (+ plain transposes for dW2/gW2/oW1)
__global__ void combine_weights(const float* __restrict__ sW2, const float* __restrict__ sb2,
                                const float* __restrict__ eW2, const float* __restrict__ eb2,
                                const float* __restrict__ gW1, const float* __restrict__ gb1,
                                const float* __restrict__ dW2, const float* __restrict__ gW2,
                                const float* __restrict__ oW1,
                                ushort* __restrict__ WT_A, ushort* __restrict__ WT_B, ushort* __restrict__ WT_E,
                                ushort* __restrict__ WT_d, ushort* __restrict__ WT_g, ushort* __restrict__ WT_o,
                                float* __restrict__ bias_A, float* __restrict__ bias_B, float* __restrict__ bias_E)
{
    const int j = threadIdx.x;
    const int i = blockIdx.x;   // 0..256 (256 = bias row)
    const int m = blockIdx.y;   // 0:A 1:B 2:E 3:dW2 4:gW2 5:oW1
    if (m>=3){
        if (i<HID){
            const float* S = (m==3)? dW2 : (m==4)? gW2 : oW1;
            ushort* D      = (m==3)? WT_d : (m==4)? WT_g : WT_o;
            D[j*HID+i]=f2bf(S[i*HID+j]);
        }
        return;
    }
    const float* L  = (m==2)? eW2 : sW2;
    const float* lb = (m==2)? eb2 : sb2;
    const float* R  = gW1 + (m==0 ? HID*HID : (m==1 ? 2*HID*HID : 0));
    float acc = 0.f;
    if (i < HID){
        for (int k=0;k<HID;k++) acc += L[i*HID+k]*R[k*HID+j];
        (m==0?WT_A:(m==1?WT_B:WT_E))[j*HID+i] = f2bf(acc);
    } else {
        for (int k=0;k<HID;k++) acc += lb[k]*R[k*HID+j];
        if (m==2) acc += gb1[j];
        (m==0?bias_A:(m==1?bias_B:bias_E))[j] = acc;
    }
}

// ---------------- node encoder (MFMA): gA/gB (bf16) + h0 (bf16)
__global__ __launch_bounds__(256) void node_encode_mfma(
    const float* __restrict__ sfeat, const float* __restrict__ dfeat,
    const float* __restrict__ sW1, const float* __restrict__ sb1,
    const float* __restrict__ dW1, const float* __restrict__ db1,
    const ushort* __restrict__ WT_d, const float* __restrict__ db2,
    const ushort* __restrict__ WT_A, const float* __restrict__ bias_A,
    const ushort* __restrict__ WT_B, const float* __restrict__ bias_B,
    ushort* __restrict__ gA, ushort* __restrict__ gB, ushort* __restrict__ h0)
{
    __shared__ ushort act[64*AS];
    __shared__ float fb[64*12];
    const int tid=threadIdx.x;
    const int n0blk=blockIdx.x*64;
    const int wv=tid>>6, lane=tid&63, n0=wv*64;
    const int colb=n0+(lane&15);

    for (int i=tid;i<64*10;i+=256){
        int n=i/10, k=i-n*10; int gn=n0blk+n;
        fb[n*10+k]=(gn<N_NODES)? sfeat[(size_t)gn*10+k]:0.f;
    }
    __syncthreads();
    {   const int j=tid;
        float w[10];
        #pragma unroll
        for (int k=0;k<10;k++) w[k]=sW1[k*HID+j];
        const float b=sb1[j];
        for (int n=0;n<64;n++){
            float a=b;
            #pragma unroll
            for (int k=0;k<10;k++) a+=fb[n*10+k]*w[k];
            act[n*AS+j]=f2bf(fmaxf(a,0.f));
        }
    }
    __syncthreads();
    f32x4 acc[4][4];
    {   // gA = act @ WT_A^T + bias_A
        wave_gemm(act, WT_A, n0, lane, acc);
        #pragma unroll
        for (int mi=0;mi<4;mi++){
            #pragma unroll
            for (int ni=0;ni<4;ni++){
                const int col=colb+ni*16; const float bA=bias_A[col];
                #pragma unroll
                for (int r=0;r<4;r++){
                    int rr=mi*16+(lane>>4)*4+r; int gn=n0blk+rr;
                    if (gn<N_NODES) gA[(size_t)gn*HID+col]=f2bf(acc[mi][ni][r]+bA);
                }
            }
        }
    }
    {   // gB
        wave_gemm(act, WT_B, n0, lane, acc);
        #pragma unroll
        for (int mi=0;mi<4;mi++){
            #pragma unroll
            for (int ni=0;ni<4;ni++){
                const int col=colb+ni*16; const float bB=bias_B[col];
                #pragma unroll
                for (int r=0;r<4;r++){
                    int rr=mi*16+(lane>>4)*4+r; int gn=n0blk+rr;
                    if (gn<N_NODES) gB[(size_t)gn*HID+col]=f2bf(acc[mi][ni][r]+bB);
                }
            }
        }
    }
    __syncthreads();
    for (int i=tid;i<64*12;i+=256){
        int n=i/12, k=i-n*12; int gn=n0blk+n;
        fb[n*12+k]=(gn<N_NODES)? dfeat[(size_t)gn*12+k]:0.f;
    }
    __syncthreads();
    {   const int j=tid;
        float w[12];
        #pragma unroll
        for (int k=0;k<12;k++) w[k]=dW1[k*HID+j];
        const float b=db1[j];
        for (int n=0;n<64;n++){
            float a=b;
            #pragma unroll
            for (int k=0;k<12;k++) a+=fb[n*12+k]*w[k];
            act[n*AS+j]=f2bf(fmaxf(a,0.f));
        }
    }
    __syncthreads();
    {   // h0 = act @ WT_d^T + db2
        wave_gemm(act, WT_d, n0, lane, acc);
        #pragma unroll
        for (int mi=0;mi<4;mi++){
            #pragma unroll
            for (int ni=0;ni<4;ni++){
                const int col=colb+ni*16; const float bo=db2[col];
                #pragma unroll
                for (int r=0;r<4;r++){
                    int rr=mi*16+(lane>>4)*4+r; int gn=n0blk+rr;
                    if (gn<N_NODES) h0[(size_t)gn*HID+col]=f2bf(acc[mi][ni][r]+bo);
                }
            }
        }
    }
}

// ---------------- edge encoder (MFMA, CSR-slot order, gA gather via global_load_lds DMA)
__global__ __launch_bounds__(256) void edge_encode_mfma(
    const float* __restrict__ eattr, const int* __restrict__ eidx,
    const int* __restrict__ csr_src, const int* __restrict__ csr_eid,
    const float* __restrict__ eW1, const float* __restrict__ eb1,
    const ushort* __restrict__ WT_E, const float* __restrict__ bias_E,
    const ushort* __restrict__ WT_g2, const float* __restrict__ gb2,
    const ushort* __restrict__ gA, const ushort* __restrict__ gB,
    ushort* __restrict__ g_out)
{
    __shared__ ushort act[64*AS];      // 33.8 KB
    __shared__ ushort gAld[64*HID];    // 32 KB: gathered gA rows (linear, DMA dest)
    __shared__ float eb[64*3];
    __shared__ int si[64], di[64];
    const int tid=threadIdx.x;
    const int s0=blockIdx.x*64;
    const int wv=tid>>6, lane=tid&63, n0=wv*64;
    const int colb=n0+(lane&15);
    const int hi=lane>>4;

    if (tid<64){
        int s=s0+tid; bool v=s<N_EDGES;
        int eid=v? csr_eid[s]:0;
        si[tid]=v? csr_src[s]:0;
        di[tid]=v? eidx[N_EDGES+eid]:0;
        float a0=0.f,a1=0.f,a2=0.f;
        if (v){ a0=eattr[(size_t)eid*3]; a1=eattr[(size_t)eid*3+1]; a2=eattr[(size_t)eid*3+2]; }
        eb[tid*3]=a0; eb[tid*3+1]=a1; eb[tid*3+2]=a2;
    }
    LDS_BAR();
    // issue gA row-gather DMA: each instr loads 2 rows (lanes 0-31 row r0, 32-63 row r0+1)
    #pragma unroll
    for (int j=0;j<8;j++){
        const int r0=__builtin_amdgcn_readfirstlane(wv*16+j*2);
        const int row=si[r0+(lane>>5)];
        gload_lds16(&gA[(size_t)row*HID+(lane&31)*8], &gAld[r0*HID]);
    }
    {   // layer1: relu(eattr@eW1+eb1) -> act
        const int j=tid;
        const float w0=eW1[j], w1=eW1[HID+j], w2=eW1[2*HID+j], b=eb1[j];
        for (int n=0;n<64;n++)
            act[n*AS+j]=f2bf(fmaxf(b+eb[n*3]*w0+eb[n*3+1]*w1+eb[n*3+2]*w2, 0.f));
    }
    LDS_BAR();
    f32x4 acc[4][4];
    wave_gemm(act, WT_E, n0, lane, acc);
    FULL_BAR();   // waves done reading act + all gA DMAs landed
    // epilogue1: + bias_E + gAld (LDS) + gB[dst] (sorted dst -> cache hits), relu -> act
    #pragma unroll
    for (int mi=0;mi<4;mi++){
        #pragma unroll
        for (int ni=0;ni<4;ni++){
            const int col=colb+ni*16; const float bE=bias_E[col];
            #pragma unroll
            for (int r=0;r<4;r++){
                const int rr=mi*16+hi*4+r;
                float vv=acc[mi][ni][r]+bE+bf2f(gAld[rr*HID+col])+bf2f(gB[(size_t)di[rr]*HID+col]);
                act[rr*AS+col]=f2bf(fmaxf(vv,0.f));
            }
        }
    }
    LDS_BAR();
    wave_gemm(act, WT_g2, n0, lane, acc);
    // epilogue2: + gb2 -> g_out[slot] (contiguous rows, coalesced)
    #pragma unroll
    for (int mi=0;mi<4;mi++){
        #pragma unroll
        for (int ni=0;ni<4;ni++){
            const int col=colb+ni*16; const float bg=gb2[col];
            #pragma unroll
            for (int r=0;r<4;r++){
                const int rr=mi*16+hi*4+r;
                if (s0+rr<N_EDGES)
                    g_out[(size_t)(s0+rr)*HID+col]=f2bf(acc[mi][ni][r]+bg);
            }
        }
    }
}

// ---------------- CSR build
__global__ void deg_count(const int* __restrict__ eidx, uint* __restrict__ deg){
    int e=blockIdx.x*blockDim.x+threadIdx.x;
    if (e<N_EDGES) atomicAdd(&deg[eidx[N_EDGES+e]],1u);
}

__global__ void scan_kernel(const uint* __restrict__ deg, uint* __restrict__ row_start){
    __shared__ uint wtot[16];
    __shared__ uint woff[17];
    __shared__ uint carry_s;
    const int tid=threadIdx.x, lane=tid&63, wid=tid>>6;
    if (tid==0) carry_s=0;
    __syncthreads();
    for (uint base=0; base<N_NODES; base+=1024){
        uint idx=base+tid;
        uint v=(idx<N_NODES)? deg[idx]:0u;
        uint s=v;
        #pragma unroll
        for (int d=1; d<64; d<<=1){
            uint t=__shfl_up(s,d,64);
            if (lane>=d) s+=t;
        }
        if (lane==63) wtot[wid]=s;
        __syncthreads();
        if (tid==0){ uint r=0; for (int i=0;i<16;i++){ woff[i]=r; r+=wtot[i]; } woff[16]=r; }
        __syncthreads();
        uint excl = carry_s + woff[wid] + s - v;
        if (idx<N_NODES) row_start[idx]=excl;
        __syncthreads();
        if (tid==0) carry_s += woff[16];
        __syncthreads();
    }
}

__global__ void csr_fill(const int* __restrict__ eidx, const uint* __restrict__ row_start,
                         uint* __restrict__ cursor, int* __restrict__ csr_src, int* __restrict__ csr_eid){
    int e=blockIdx.x*blockDim.x+threadIdx.x;
    if (e>=N_EDGES) return;
    int d=eidx[N_EDGES+e];
    uint pos=atomicAdd(&cursor[d],1u);
    uint s=row_start[d]+pos;
    csr_src[s]=eidx[e];
    csr_eid[s]=e;
}

// ---------------- message-passing hop: one wave per node, CSR gather, bf16 h in/out
__global__ __launch_bounds__(256) void hop_kernel(
    const ushort* __restrict__ h_in, ushort* __restrict__ h_out,
    const ushort* __restrict__ g, const int* __restrict__ csr_src,
    const uint* __restrict__ row_start, const uint* __restrict__ deg)
{
    const int gw=(blockIdx.x*blockDim.x+threadIdx.x)>>6;
    if (gw>=N_NODES) return;
    const int c0=(threadIdx.x&63)*4;
    ushort4 hd4=*(const ushort4*)&h_in[(size_t)gw*HID+c0];
    float4 hd; hd.x=bf2f(hd4.x); hd.y=bf2f(hd4.y); hd.z=bf2f(hd4.z); hd.w=bf2f(hd4.w);
    float4 acc=make_float4(0,0,0,0);
    const uint st=row_start[gw], len=deg[gw];
    for (uint u=0;u<len;u++){
        uint s=st+u;
        int sn=csr_src[s];
        ushort4 g4=*(const ushort4*)&g[(size_t)s*HID+c0];
        ushort4 hs4=*(const ushort4*)&h_in[(size_t)sn*HID+c0];
        acc.x += bf2f(g4.x)*(bf2f(hs4.x)-hd.x);
        acc.y += bf2f(g4.y)*(bf2f(hs4.y)-hd.y);
        acc.z += bf2f(g4.z)*(bf2f(hs4.z)-hd.z);
        acc.w += bf2f(g4.w)*(bf2f(hs4.w)-hd.w);
    }
    const float inv=1.f/fmaxf((float)len,1.f);
    ushort4 o; o.x=f2bf(hd.x+acc.x*inv); o.y=f2bf(hd.y+acc.y*inv);
               o.z=f2bf(hd.z+acc.z*inv); o.w=f2bf(hd.w+acc.w*inv);
    *(ushort4*)&h_out[(size_t)gw*HID+c0]=o;
}

// ---------------- decoder (MFMA): out = relu(tanh(h)@oW1+ob1)@oW2+ob2
__global__ __launch_bounds__(256) void decoder_mfma(
    const ushort* __restrict__ h, const ushort* __restrict__ WT_o,
    const float* __restrict__ ob1, const float* __restrict__ oW2, const float* __restrict__ ob2,
    float* __restrict__ out)
{
    __shared__ ushort act[64*AS];
    const int tid=threadIdx.x, n0blk=blockIdx.x*64;
    const int wv=tid>>6, lane=tid&63, n0=wv*64, colb=n0+(lane&15);
    {   // stage tanh(h) -> act (bf16); 4 threads per row, 64 cols each
        const int row=tid>>2, cc=(tid&3)*64;
        const int gn=n0blk+row;
        #pragma unroll
        for (int k=0;k<64;k+=8){
            u16x8 t;
            if (gn<N_NODES){
                u16x8 v=*(const u16x8*)&h[(size_t)gn*HID+cc+k];
                #pragma unroll
                for (int j=0;j<8;j++) t[j]=f2bf(tanhf(bf2f(v[j])));
            } else {
                #pragma unroll
                for (int j=0;j<8;j++) t[j]=0;
            }
            *(u16x8*)&act[row*AS+cc+k]=t;
        }
    }
    __syncthreads();
    f32x4 acc[4][4];
    wave_gemm(act, WT_o, n0, lane, acc);
    __syncthreads();
    #pragma unroll
    for (int mi=0;mi<4;mi++){
        #pragma unroll
        for (int ni=0;ni<4;ni++){
            const int col=colb+ni*16; const float b1=ob1[col];
            #pragma unroll
            for (int r=0;r<4;r++){
                const int rr=mi*16+(lane>>4)*4+r;
                act[rr*AS+col]=f2bf(fmaxf(acc[mi][ni][r]+b1,0.f));
            }
        }
    }
    __syncthreads();
    if (tid<192){
        const int n=tid/3, o=tid-n*3;
        float a=ob2[o];
        for (int k=0;k<HID;k++) a+=bf2f(act[n*AS+k])*oW2[k*3+o];
        const int gn=n0blk+n;
        if (gn<N_NODES) out[(size_t)gn*3+o]=a;
    }
}

extern "C" void kernel_launch(void* const* d_in, const int* in_sizes, int n_in,
                              void* d_out, int out_size, void* d_ws, size_t ws_size,
                              hipStream_t stream)
{
    (void)in_sizes; (void)n_in; (void)out_size;
    const float* sfeat=(const float*)d_in[0];
    const float* dfeat=(const float*)d_in[1];
    const int*   eidx =(const int*)  d_in[2];
    const float* eattr=(const float*)d_in[3];
    const float* sW1=(const float*)d_in[4];  const float* sb1=(const float*)d_in[5];
    const float* sW2=(const float*)d_in[6];  const float* sb2=(const float*)d_in[7];
    const float* dW1=(const float*)d_in[8];  const float* db1=(const float*)d_in[9];
    const float* dW2=(const float*)d_in[10]; const float* db2=(const float*)d_in[11];
    const float* eW1=(const float*)d_in[12]; const float* eb1=(const float*)d_in[13];
    const float* eW2=(const float*)d_in[14]; const float* eb2=(const float*)d_in[15];
    const float* gW1=(const float*)d_in[16]; const float* gb1=(const float*)d_in[17];
    const float* gW2=(const float*)d_in[18]; const float* gb2=(const float*)d_in[19];
    const float* oW1=(const float*)d_in[20]; const float* ob1=(const float*)d_in[21];
    const float* oW2=(const float*)d_in[22]; const float* ob2=(const float*)d_in[23];
    float* out=(float*)d_out;

    char* p=(char*)d_ws;
    size_t used=0;
    auto alloc=[&](size_t bytes)->char*{
        char* r=p+used; used += (bytes+255)&~(size_t)255; return r;
    };
    ushort* WT_A=(ushort*)alloc(HID*HID*2);
    ushort* WT_B=(ushort*)alloc(HID*HID*2);
    ushort* WT_E=(ushort*)alloc(HID*HID*2);
    ushort* WT_d=(ushort*)alloc(HID*HID*2);
    ushort* WT_g=(ushort*)alloc(HID*HID*2);
    ushort* WT_o=(ushort*)alloc(HID*HID*2);
    float* bias_A=(float*)alloc(HID*4);
    float* bias_B=(float*)alloc(HID*4);
    float* bias_E=(float*)alloc(HID*4);
    ushort* gA=(ushort*)alloc((size_t)N_NODES*HID*2);
    ushort* gB=(ushort*)alloc((size_t)N_NODES*HID*2);
    ushort* g =(ushort*)alloc((size_t)N_EDGES*HID*2);
    ushort* h0=(ushort*)alloc((size_t)N_NODES*HID*2);
    uint* deg      =(uint*)alloc(N_NODES*4);
    uint* row_start=(uint*)alloc(N_NODES*4);
    uint* cursor   =(uint*)alloc(N_NODES*4);
    int* csr_src=(int*)alloc(N_EDGES*4);
    int* csr_eid=(int*)alloc(N_EDGES*4);
    ushort* h1=gA;   // alias: gA/gB dead after edge_encode

    if (used > ws_size) return;  // clean fail if ws too small

    hipMemsetAsync(deg, 0, N_NODES*4, stream);
    hipMemsetAsync(cursor, 0, N_NODES*4, stream);

    combine_weights<<<dim3(HID+1,6),256,0,stream>>>(sW2,sb2,eW2,eb2,gW1,gb1,dW2,gW2,oW1,
                                                    WT_A,WT_B,WT_E,WT_d,WT_g,WT_o,bias_A,bias_B,bias_E);
    node_encode_mfma<<<(N_NODES+63)/64,256,0,stream>>>(sfeat,dfeat,sW1,sb1,dW1,db1,WT_d,db2,WT_A,bias_A,WT_B,bias_B,gA,gB,h0);
    deg_count<<<(N_EDGES+255)/256,256,0,stream>>>(eidx,deg);
    scan_kernel<<<1,1024,0,stream>>>(deg,row_start);
    csr_fill<<<(N_EDGES+255)/256,256,0,stream>>>(eidx,row_start,cursor,csr_src,csr_eid);
    edge_encode_mfma<<<(N_EDGES+63)/64,256,0,stream>>>(eattr,eidx,csr_src,csr_eid,eW1,eb1,WT_E,bias_E,WT_g,gb2,gA,gB,g);
    hop_kernel<<<N_NODES/4,256,0,stream>>>(h0,h1,g,csr_src,row_start,deg);
    hop_kernel<<<N_NODES/4,256,0,stream>>>(h1,h0,g,csr_src,row_start,deg);
    decoder_mfma<<<(N_NODES+63)/64,256,0,stream>>>(h0,WT_o,ob1,oW2,ob2,out);
}

// Round 6
// 593.367 us; speedup vs baseline: 2.6810x; 1.1009x over previous
//
#include <hip/hip_runtime.h>
#include <hip/hip_bf16.h>

#define N_NODES 50000
#define N_EDGES 300000
#define HID 256
#define AS 264      // LDS act stride in bf16 elems: 264*2=528B = 33*16 -> 16B-aligned rows
#define A0S 40      // A0 stride (ushorts): 80B rows, 16B-aligned, bank-friendly
#define TN 32

typedef unsigned int uint;
typedef unsigned short ushort;
typedef short bf16x8 __attribute__((ext_vector_type(8)));
typedef unsigned short u16x8 __attribute__((ext_vector_type(8)));
typedef float f32x4 __attribute__((ext_vector_type(4)));

__device__ __forceinline__ float bf2f(ushort u){ union{uint i; float f;} v; v.i=((uint)u)<<16; return v.f; }
__device__ __forceinline__ ushort f2bf(float f){ __hip_bfloat16 h=__float2bfloat16(f); return *reinterpret_cast<ushort*>(&h); }

__device__ __forceinline__ f32x4 mfma16(bf16x8 a, bf16x8 b, f32x4 c){
    return __builtin_amdgcn_mfma_f32_16x16x32_bf16(a, b, c, 0, 0, 0);
}

// wave computes rows 0..63 (A in LDS, row-major stride AS) x cols [n0,n0+64) of WT (bf16 [N][K=256] row-major)
__device__ __forceinline__ void wave_gemm(const ushort* act, const ushort* __restrict__ WT,
                                          int n0, int lane, f32x4 acc[4][4])
{
    #pragma unroll
    for (int mi=0;mi<4;mi++)
        #pragma unroll
        for (int ni=0;ni<4;ni++) acc[mi][ni]=(f32x4){0.f,0.f,0.f,0.f};
    const int rA=lane&15, kg=(lane>>4)*8;
    #pragma unroll
    for (int kk=0;kk<8;kk++){
        const int ka=kk*32+kg;
        bf16x8 a[4], b[4];
        #pragma unroll
        for (int mi=0;mi<4;mi++) a[mi]=*(const bf16x8*)&act[(mi*16+rA)*AS+ka];
        #pragma unroll
        for (int ni=0;ni<4;ni++) b[ni]=*(const bf16x8*)&WT[(size_t)((n0+ni*16+rA)*HID+ka)];
        #pragma unroll
        for (int mi=0;mi<4;mi++)
            #pragma unroll
            for (int ni=0;ni<4;ni++)
                acc[mi][ni]=mfma16(a[mi], b[ni], acc[mi][ni]);
    }
}

// scatter C-layout accumulator into act LDS (scalar b16 writes), optional relu
__device__ __forceinline__ void store_c_to_act(ushort* act, const f32x4 acc[4][4],
                                               int colb, int hi, bool relu)
{
    #pragma unroll
    for (int mi=0;mi<4;mi++)
        #pragma unroll
        for (int ni=0;ni<4;ni++)
            #pragma unroll
            for (int r=0;r<4;r++){
                float v=acc[mi][ni][r];
                if (relu) v=fmaxf(v,0.f);
                act[(mi*16+hi*4+r)*AS + colb+ni*16]=f2bf(v);
            }
}

// ---------------- combined weights -> bf16 transposed (+WT_e1 with eW1/eb1 folded, all biases folded into bias_A)
__global__ void combine_weights(const float* __restrict__ sW2, const float* __restrict__ sb2,
                                const float* __restrict__ eW2, const float* __restrict__ eb2,
                                const float* __restrict__ gW1, const float* __restrict__ gb1,
                                const float* __restrict__ dW2, const float* __restrict__ gW2,
                                const float* __restrict__ oW1,
                                const float* __restrict__ eW1, const float* __restrict__ eb1,
                                ushort* __restrict__ WT_A, ushort* __restrict__ WT_B, ushort* __restrict__ WT_E,
                                ushort* __restrict__ WT_d, ushort* __restrict__ WT_g, ushort* __restrict__ WT_o,
                                ushort* __restrict__ WT_e1,
                                float* __restrict__ bias_A, float* __restrict__ bias_B)
{
    const int j = threadIdx.x;
    const int i = blockIdx.x;   // 0..256 (256 = bias row for m<3)
    const int m = blockIdx.y;   // 0:A 1:B 2:E 3:dW2 4:gW2 5:oW1 6:e1
    if (m==6){
        if (i<32)
            WT_e1[j*32+i] = f2bf(i<3 ? eW1[i*HID+j] : (i==3 ? eb1[j] : 0.f));
        return;
    }
    if (m>=3){
        if (i<HID){
            const float* S = (m==3)? dW2 : (m==4)? gW2 : oW1;
            ushort* D      = (m==3)? WT_d : (m==4)? WT_g : WT_o;
            D[j*HID+i]=f2bf(S[i*HID+j]);
        }
        return;
    }
    const float* L  = (m==2)? eW2 : sW2;
    const float* R  = gW1 + (m==0 ? HID*HID : (m==1 ? 2*HID*HID : 0));
    if (i < HID){
        float acc=0.f;
        for (int k=0;k<HID;k++) acc += L[i*HID+k]*R[k*HID+j];
        (m==0?WT_A:(m==1?WT_B:WT_E))[j*HID+i] = f2bf(acc);
    } else if (m==0){
        // bias_A_total = sb2@gW1_A + eb2@gW1_E + gb1  (bias_B folded separately)
        float acc=gb1[j];
        for (int k=0;k<HID;k++) acc += sb2[k]*gW1[(HID+k)*HID+j];
        for (int k=0;k<HID;k++) acc += eb2[k]*gW1[k*HID+j];
        bias_A[j]=acc;
    } else if (m==1){
        float acc=0.f;
        for (int k=0;k<HID;k++) acc += sb2[k]*gW1[(2*HID+k)*HID+j];
        bias_B[j]=acc;
    }
}

// ---------------- node encoder (MFMA): gA/gB (bf16) + h0 (bf16)
__global__ __launch_bounds__(256) void node_encode_mfma(
    const float* __restrict__ sfeat, const float* __restrict__ dfeat,
    const float* __restrict__ sW1, const float* __restrict__ sb1,
    const float* __restrict__ dW1, const float* __restrict__ db1,
    const ushort* __restrict__ WT_d, const float* __restrict__ db2,
    const ushort* __restrict__ WT_A, const float* __restrict__ bias_A,
    const ushort* __restrict__ WT_B, const float* __restrict__ bias_B,
    ushort* __restrict__ gA, ushort* __restrict__ gB, ushort* __restrict__ h0)
{
    __shared__ ushort act[64*AS];
    __shared__ float fb[64*12];
    const int tid=threadIdx.x;
    const int n0blk=blockIdx.x*64;
    const int wv=tid>>6, lane=tid&63, n0=wv*64;
    const int colb=n0+(lane&15);

    for (int i=tid;i<64*10;i+=256){
        int n=i/10, k=i-n*10; int gn=n0blk+n;
        fb[n*10+k]=(gn<N_NODES)? sfeat[(size_t)gn*10+k]:0.f;
    }
    __syncthreads();
    {   const int j=tid;
        float w[10];
        #pragma unroll
        for (int k=0;k<10;k++) w[k]=sW1[k*HID+j];
        const float b=sb1[j];
        for (int n=0;n<64;n++){
            float a=b;
            #pragma unroll
            for (int k=0;k<10;k++) a+=fb[n*10+k]*w[k];
            act[n*AS+j]=f2bf(fmaxf(a,0.f));
        }
    }
    __syncthreads();
    f32x4 acc[4][4];
    {   // gA = act @ WT_A^T + bias_A(total)
        wave_gemm(act, WT_A, n0, lane, acc);
        #pragma unroll
        for (int mi=0;mi<4;mi++){
            #pragma unroll
            for (int ni=0;ni<4;ni++){
                const int col=colb+ni*16; const float bA=bias_A[col];
                #pragma unroll
                for (int r=0;r<4;r++){
                    int rr=mi*16+(lane>>4)*4+r; int gn=n0blk+rr;
                    if (gn<N_NODES) gA[(size_t)gn*HID+col]=f2bf(acc[mi][ni][r]+bA);
                }
            }
        }
    }
    {   // gB
        wave_gemm(act, WT_B, n0, lane, acc);
        #pragma unroll
        for (int mi=0;mi<4;mi++){
            #pragma unroll
            for (int ni=0;ni<4;ni++){
                const int col=colb+ni*16; const float bB=bias_B[col];
                #pragma unroll
                for (int r=0;r<4;r++){
                    int rr=mi*16+(lane>>4)*4+r; int gn=n0blk+rr;
                    if (gn<N_NODES) gB[(size_t)gn*HID+col]=f2bf(acc[mi][ni][r]+bB);
                }
            }
        }
    }
    __syncthreads();
    for (int i=tid;i<64*12;i+=256){
        int n=i/12, k=i-n*12; int gn=n0blk+n;
        fb[n*12+k]=(gn<N_NODES)? dfeat[(size_t)gn*12+k]:0.f;
    }
    __syncthreads();
    {   const int j=tid;
        float w[12];
        #pragma unroll
        for (int k=0;k<12;k++) w[k]=dW1[k*HID+j];
        const float b=db1[j];
        for (int n=0;n<64;n++){
            float a=b;
            #pragma unroll
            for (int k=0;k<12;k++) a+=fb[n*12+k]*w[k];
            act[n*AS+j]=f2bf(fmaxf(a,0.f));
        }
    }
    __syncthreads();
    {   // h0 = act @ WT_d^T + db2
        wave_gemm(act, WT_d, n0, lane, acc);
        #pragma unroll
        for (int mi=0;mi<4;mi++){
            #pragma unroll
            for (int ni=0;ni<4;ni++){
                const int col=colb+ni*16; const float bo=db2[col];
                #pragma unroll
                for (int r=0;r<4;r++){
                    int rr=mi*16+(lane>>4)*4+r; int gn=n0blk+rr;
                    if (gn<N_NODES) h0[(size_t)gn*HID+col]=f2bf(acc[mi][ni][r]+bo);
                }
            }
        }
    }
}

// ---------------- edge encoder: all-MFMA + vectorized remap, CSR-slot order
__global__ __launch_bounds__(256) void edge_encode_mfma(
    const float* __restrict__ eattr, const int* __restrict__ eidx,
    const int* __restrict__ csr_src, const int* __restrict__ csr_eid,
    const ushort* __restrict__ WT_e1,
    const ushort* __restrict__ WT_E,
    const ushort* __restrict__ WT_g2, const float* __restrict__ gb2,
    const ushort* __restrict__ gA, const ushort* __restrict__ gB,
    ushort* __restrict__ g_out)
{
    __shared__ ushort act[64*AS];     // 33.8 KB
    __shared__ ushort A0[64*A0S];     // 5.1 KB
    __shared__ int si[64], di[64], ei[64];
    const int tid=threadIdx.x;
    const int s0=blockIdx.x*64;
    const int wv=tid>>6, lane=tid&63, n0=wv*64;
    const int rA=lane&15, kg=(lane>>4)*8, hi=lane>>4;
    const int colb=n0+rA;

    if (tid<64){
        int s=s0+tid; bool v=s<N_EDGES;
        int eid=v? csr_eid[s]:0;
        si[tid]=v? csr_src[s]:0;
        di[tid]=v? eidx[N_EDGES+eid]:0;
        ei[tid]=eid;
    }
    __syncthreads();
    {   // stage A0 = [eattr0,eattr1,eattr2,1,0...0]  (bias column k=3)
        const int n=tid>>2, k0=(tid&3)*8;
        const int eid=ei[n];
        u16x8 v;
        #pragma unroll
        for (int j=0;j<8;j++){
            const int k=k0+j;
            float f = (k<3)? eattr[(size_t)eid*3+k] : (k==3? 1.f : 0.f);
            v[j]=f2bf(f);
        }
        *(u16x8*)&A0[n*A0S+k0]=v;
    }
    __syncthreads();
    f32x4 acc[4][4];
    {   // gemm0: e1 = relu(A0 @ WT_e1^T), K=32
        #pragma unroll
        for (int mi=0;mi<4;mi++)
            #pragma unroll
            for (int ni=0;ni<4;ni++) acc[mi][ni]=(f32x4){0.f,0.f,0.f,0.f};
        bf16x8 a[4], b[4];
        #pragma unroll
        for (int mi=0;mi<4;mi++) a[mi]=*(const bf16x8*)&A0[(mi*16+rA)*A0S+kg];
        #pragma unroll
        for (int ni=0;ni<4;ni++) b[ni]=*(const bf16x8*)&WT_e1[(size_t)(n0+ni*16+rA)*32+kg];
        #pragma unroll
        for (int mi=0;mi<4;mi++)
            #pragma unroll
            for (int ni=0;ni<4;ni++)
                acc[mi][ni]=mfma16(a[mi], b[ni], acc[mi][ni]);
        store_c_to_act(act, acc, colb, hi, true);
    }
    __syncthreads();
    wave_gemm(act, WT_E, n0, lane, acc);    // gemm1
    __syncthreads();                        // all waves done reading act
    store_c_to_act(act, acc, colb, hi, false);  // raw acc1
    __syncthreads();
    {   // remap1: act = relu(act + gA[src] + gB[dst])   (row-wise, vectorized)
        const int n=tid>>2, cc=(tid&3)*64;
        const int s=si[n], d=di[n];
        #pragma unroll
        for (int j=0;j<8;j++){
            u16x8 av=*(u16x8*)&act[n*AS+cc+j*8];
            u16x8 ga=*(const u16x8*)&gA[(size_t)s*HID+cc+j*8];
            u16x8 gb=*(const u16x8*)&gB[(size_t)d*HID+cc+j*8];
            u16x8 o;
            #pragma unroll
            for (int q=0;q<8;q++)
                o[q]=f2bf(fmaxf(bf2f(av[q])+bf2f(ga[q])+bf2f(gb[q]),0.f));
            *(u16x8*)&act[n*AS+cc+j*8]=o;
        }
    }
    __syncthreads();
    wave_gemm(act, WT_g2, n0, lane, acc);   // gemm2
    {   // epilogue: + gb2 -> g_out[slot] (C-layout direct stores)
        #pragma unroll
        for (int mi=0;mi<4;mi++){
            #pragma unroll
            for (int ni=0;ni<4;ni++){
                const int col=colb+ni*16; const float bg=gb2[col];
                #pragma unroll
                for (int r=0;r<4;r++){
                    const int rr=mi*16+hi*4+r;
                    if (s0+rr<N_EDGES)
                        g_out[(size_t)(s0+rr)*HID+col]=f2bf(acc[mi][ni][r]+bg);
                }
            }
        }
    }
}

// ---------------- CSR build
__global__ void deg_count(const int* __restrict__ eidx, uint* __restrict__ deg){
    int e=blockIdx.x*blockDim.x+threadIdx.x;
    if (e<N_EDGES) atomicAdd(&deg[eidx[N_EDGES+e]],1u);
}

__global__ void scan_kernel(const uint* __restrict__ deg, uint* __restrict__ row_start){
    __shared__ uint wtot[16];
    __shared__ uint woff[17];
    __shared__ uint carry_s;
    const int tid=threadIdx.x, lane=tid&63, wid=tid>>6;
    if (tid==0) carry_s=0;
    __syncthreads();
    for (uint base=0; base<N_NODES; base+=1024){
        uint idx=base+tid;
        uint v=(idx<N_NODES)? deg[idx]:0u;
        uint s=v;
        #pragma unroll
        for (int d=1; d<64; d<<=1){
            uint t=__shfl_up(s,d,64);
            if (lane>=d) s+=t;
        }
        if (lane==63) wtot[wid]=s;
        __syncthreads();
        if (tid==0){ uint r=0; for (int i=0;i<16;i++){ woff[i]=r; r+=wtot[i]; } woff[16]=r; }
        __syncthreads();
        uint excl = carry_s + woff[wid] + s - v;
        if (idx<N_NODES) row_start[idx]=excl;
        __syncthreads();
        if (tid==0) carry_s += woff[16];
        __syncthreads();
    }
}

__global__ void csr_fill(const int* __restrict__ eidx, const uint* __restrict__ row_start,
                         uint* __restrict__ cursor, int* __restrict__ csr_src, int* __restrict__ csr_eid){
    int e=blockIdx.x*blockDim.x+threadIdx.x;
    if (e>=N_EDGES) return;
    int d=eidx[N_EDGES+e];
    uint pos=atomicAdd(&cursor[d],1u);
    uint s=row_start[d]+pos;
    csr_src[s]=eidx[e];
    csr_eid[s]=e;
}

// ---------------- message-passing hop: one wave per node, CSR gather, bf16 h in/out
__global__ __launch_bounds__(256) void hop_kernel(
    const ushort* __restrict__ h_in, ushort* __restrict__ h_out,
    const ushort* __restrict__ g, const int* __restrict__ csr_src,
    const uint* __restrict__ row_start, const uint* __restrict__ deg)
{
    const int gw=(blockIdx.x*blockDim.x+threadIdx.x)>>6;
    if (gw>=N_NODES) return;
    const int c0=(threadIdx.x&63)*4;
    ushort4 hd4=*(const ushort4*)&h_in[(size_t)gw*HID+c0];
    float4 hd; hd.x=bf2f(hd4.x); hd.y=bf2f(hd4.y); hd.z=bf2f(hd4.z); hd.w=bf2f(hd4.w);
    float4 acc=make_float4(0,0,0,0);
    const uint st=row_start[gw], len=deg[gw];
    for (uint u=0;u<len;u++){
        uint s=st+u;
        int sn=csr_src[s];
        ushort4 g4=*(const ushort4*)&g[(size_t)s*HID+c0];
        ushort4 hs4=*(const ushort4*)&h_in[(size_t)sn*HID+c0];
        acc.x += bf2f(g4.x)*(bf2f(hs4.x)-hd.x);
        acc.y += bf2f(g4.y)*(bf2f(hs4.y)-hd.y);
        acc.z += bf2f(g4.z)*(bf2f(hs4.z)-hd.z);
        acc.w += bf2f(g4.w)*(bf2f(hs4.w)-hd.w);
    }
    const float inv=1.f/fmaxf((float)len,1.f);
    ushort4 o; o.x=f2bf(hd.x+acc.x*inv); o.y=f2bf(hd.y+acc.y*inv);
               o.z=f2bf(hd.z+acc.z*inv); o.w=f2bf(hd.w+acc.w*inv);
    *(ushort4*)&h_out[(size_t)gw*HID+c0]=o;
}

// ---------------- decoder (MFMA): out = relu(tanh(h)@oW1+ob1)@oW2+ob2
__global__ __launch_bounds__(256) void decoder_mfma(
    const ushort* __restrict__ h, const ushort* __restrict__ WT_o,
    const float* __restrict__ ob1, const float* __restrict__ oW2, const float* __restrict__ ob2,
    float* __restrict__ out)
{
    __shared__ ushort act[64*AS];
    const int tid=threadIdx.x, n0blk=blockIdx.x*64;
    const int wv=tid>>6, lane=tid&63, n0=wv*64, colb=n0+(lane&15);
    {   // stage tanh(h) -> act (bf16)
        const int row=tid>>2, cc=(tid&3)*64;
        const int gn=n0blk+row;
        #pragma unroll
        for (int k=0;k<64;k+=8){
            u16x8 t;
            if (gn<N_NODES){
                u16x8 v=*(const u16x8*)&h[(size_t)gn*HID+cc+k];
                #pragma unroll
                for (int j=0;j<8;j++) t[j]=f2bf(tanhf(bf2f(v[j])));
            } else {
                #pragma unroll
                for (int j=0;j<8;j++) t[j]=0;
            }
            *(u16x8*)&act[row*AS+cc+k]=t;
        }
    }
    __syncthreads();
    f32x4 acc[4][4];
    wave_gemm(act, WT_o, n0, lane, acc);
    __syncthreads();
    #pragma unroll
    for (int mi=0;mi<4;mi++){
        #pragma unroll
        for (int ni=0;ni<4;ni++){
            const int col=colb+ni*16; const float b1=ob1[col];
            #pragma unroll
            for (int r=0;r<4;r++){
                const int rr=mi*16+(lane>>4)*4+r;
                act[rr*AS+col]=f2bf(fmaxf(acc[mi][ni][r]+b1,0.f));
            }
        }
    }
    __syncthreads();
    if (tid<192){
        const int n=tid/3, o=tid-n*3;
        float a=ob2[o];
        for (int k=0;k<HID;k++) a+=bf2f(act[n*AS+k])*oW2[k*3+o];
        const int gn=n0blk+n;
        if (gn<N_NODES) out[(size_t)gn*3+o]=a;
    }
}

extern "C" void kernel_launch(void* const* d_in, const int* in_sizes, int n_in,
                              void* d_out, int out_size, void* d_ws, size_t ws_size,
                              hipStream_t stream)
{
    (void)in_sizes; (void)n_in; (void)out_size;
    const float* sfeat=(const float*)d_in[0];
    const float* dfeat=(const float*)d_in[1];
    const int*   eidx =(const int*)  d_in[2];
    const float* eattr=(const float*)d_in[3];
    const float* sW1=(const float*)d_in[4];  const float* sb1=(const float*)d_in[5];
    const float* sW2=(const float*)d_in[6];  const float* sb2=(const float*)d_in[7];
    const float* dW1=(const float*)d_in[8];  const float* db1=(const float*)d_in[9];
    const float* dW2=(const float*)d_in[10]; const float* db2=(const float*)d_in[11];
    const float* eW1=(const float*)d_in[12]; const float* eb1=(const float*)d_in[13];
    const float* eW2=(const float*)d_in[14]; const float* eb2=(const float*)d_in[15];
    const float* gW1=(const float*)d_in[16]; const float* gb1=(const float*)d_in[17];
    const float* gW2=(const float*)d_in[18]; const float* gb2=(const float*)d_in[19];
    const float* oW1=(const float*)d_in[20]; const float* ob1=(const float*)d_in[21];
    const float* oW2=(const float*)d_in[22]; const float* ob2=(const float*)d_in[23];
    float* out=(float*)d_out;

    char* p=(char*)d_ws;
    size_t used=0;
    auto alloc=[&](size_t bytes)->char*{
        char* r=p+used; used += (bytes+255)&~(size_t)255; return r;
    };
    ushort* WT_A=(ushort*)alloc(HID*HID*2);
    ushort* WT_B=(ushort*)alloc(HID*HID*2);
    ushort* WT_E=(ushort*)alloc(HID*HID*2);
    ushort* WT_d=(ushort*)alloc(HID*HID*2);
    ushort* WT_g=(ushort*)alloc(HID*HID*2);
    ushort* WT_o=(ushort*)alloc(HID*HID*2);
    ushort* WT_e1=(ushort*)alloc(HID*32*2);
    float* bias_A=(float*)alloc(HID*4);
    float* bias_B=(float*)alloc(HID*4);
    ushort* gA=(ushort*)alloc((size_t)N_NODES*HID*2);
    ushort* gB=(ushort*)alloc((size_t)N_NODES*HID*2);
    ushort* g =(ushort*)alloc((size_t)N_EDGES*HID*2);
    ushort* h0=(ushort*)alloc((size_t)N_NODES*HID*2);
    uint* deg      =(uint*)alloc(N_NODES*4);
    uint* row_start=(uint*)alloc(N_NODES*4);
    uint* cursor   =(uint*)alloc(N_NODES*4);
    int* csr_src=(int*)alloc(N_EDGES*4);
    int* csr_eid=(int*)alloc(N_EDGES*4);
    ushort* h1=gA;   // alias: gA/gB dead after edge_encode

    if (used > ws_size) return;  // clean fail if ws too small

    hipMemsetAsync(deg, 0, N_NODES*4, stream);
    hipMemsetAsync(cursor, 0, N_NODES*4, stream);

    combine_weights<<<dim3(HID+1,7),256,0,stream>>>(sW2,sb2,eW2,eb2,gW1,gb1,dW2,gW2,oW1,eW1,eb1,
                                                    WT_A,WT_B,WT_E,WT_d,WT_g,WT_o,WT_e1,bias_A,bias_B);
    node_encode_mfma<<<(N_NODES+63)/64,256,0,stream>>>(sfeat,dfeat,sW1,sb1,dW1,db1,WT_d,db2,WT_A,bias_A,WT_B,bias_B,gA,gB,h0);
    deg_count<<<(N_EDGES+255)/256,256,0,stream>>>(eidx,deg);
    scan_kernel<<<1,1024,0,stream>>>(deg,row_start);
    csr_fill<<<(N_EDGES+255)/256,256,0,stream>>>(eidx,row_start,cursor,csr_src,csr_eid);
    edge_encode_mfma<<<(N_EDGES+63)/64,256,0,stream>>>(eattr,eidx,csr_src,csr_eid,WT_e1,WT_E,WT_g,gb2,gA,gB,g);
    hop_kernel<<<N_NODES/4,256,0,stream>>>(h0,h1,g,csr_src,row_start,deg);
    hop_kernel<<<N_NODES/4,256,0,stream>>>(h1,h0,g,csr_src,row_start,deg);
    decoder_mfma<<<(N_NODES+63)/64,256,0,stream>>>(h0,WT_o,ob1,oW2,ob2,out);
}

// Round 7
// 591.888 us; speedup vs baseline: 2.6877x; 1.0025x over previous
//
#include <hip/hip_runtime.h>
#include <hip/hip_bf16.h>

#define N_NODES 50000
#define N_EDGES 300000
#define HID 256
#define AS 264      // LDS act stride in bf16 elems: 264*2=528B = 33*16 -> 16B-aligned rows
#define A0S 40      // A0 stride (ushorts): 80B rows, 16B-aligned

typedef unsigned int uint;
typedef unsigned short ushort;
typedef short bf16x8 __attribute__((ext_vector_type(8)));
typedef unsigned short u16x8 __attribute__((ext_vector_type(8)));
typedef float f32x4 __attribute__((ext_vector_type(4)));

__device__ __forceinline__ float bf2f(ushort u){ union{uint i; float f;} v; v.i=((uint)u)<<16; return v.f; }
__device__ __forceinline__ ushort f2bf(float f){ __hip_bfloat16 h=__float2bfloat16(f); return *reinterpret_cast<ushort*>(&h); }

__device__ __forceinline__ f32x4 mfma16(bf16x8 a, bf16x8 b, f32x4 c){
    return __builtin_amdgcn_mfma_f32_16x16x32_bf16(a, b, c, 0, 0, 0);
}

// wave computes rows 0..63 (A in LDS, row-major stride AS) x cols [n0,n0+64) of WT (bf16 [N][K=256] row-major)
__device__ __forceinline__ void wave_gemm(const ushort* act, const ushort* __restrict__ WT,
                                          int n0, int lane, f32x4 acc[4][4])
{
    #pragma unroll
    for (int mi=0;mi<4;mi++)
        #pragma unroll
        for (int ni=0;ni<4;ni++) acc[mi][ni]=(f32x4){0.f,0.f,0.f,0.f};
    const int rA=lane&15, kg=(lane>>4)*8;
    __builtin_amdgcn_s_setprio(1);
    #pragma unroll
    for (int kk=0;kk<8;kk++){
        const int ka=kk*32+kg;
        bf16x8 a[4], b[4];
        #pragma unroll
        for (int mi=0;mi<4;mi++) a[mi]=*(const bf16x8*)&act[(mi*16+rA)*AS+ka];
        #pragma unroll
        for (int ni=0;ni<4;ni++) b[ni]=*(const bf16x8*)&WT[(size_t)((n0+ni*16+rA)*HID+ka)];
        #pragma unroll
        for (int mi=0;mi<4;mi++)
            #pragma unroll
            for (int ni=0;ni<4;ni++)
                acc[mi][ni]=mfma16(a[mi], b[ni], acc[mi][ni]);
    }
    __builtin_amdgcn_s_setprio(0);
}

// gemm with K=32 A0 tile (LDS, stride A0S) x WT32 (bf16 [256][32])
__device__ __forceinline__ void wave_gemm32(const ushort* A0, const ushort* __restrict__ WT32,
                                            int n0, int lane, f32x4 acc[4][4])
{
    const int rA=lane&15, kg=(lane>>4)*8;
    bf16x8 a[4], b[4];
    #pragma unroll
    for (int mi=0;mi<4;mi++) a[mi]=*(const bf16x8*)&A0[(mi*16+rA)*A0S+kg];
    #pragma unroll
    for (int ni=0;ni<4;ni++) b[ni]=*(const bf16x8*)&WT32[(size_t)(n0+ni*16+rA)*32+kg];
    __builtin_amdgcn_s_setprio(1);
    #pragma unroll
    for (int mi=0;mi<4;mi++)
        #pragma unroll
        for (int ni=0;ni<4;ni++)
            acc[mi][ni]=mfma16(a[mi], b[ni], (f32x4){0.f,0.f,0.f,0.f}), void(0);
    __builtin_amdgcn_s_setprio(0);
    // note: rewritten without comma trick below for clarity
}

// scatter C-layout accumulator into act LDS (scalar b16 writes), optional relu
__device__ __forceinline__ void store_c_to_act(ushort* act, const f32x4 acc[4][4],
                                               int colb, int hi, bool relu)
{
    #pragma unroll
    for (int mi=0;mi<4;mi++)
        #pragma unroll
        for (int ni=0;ni<4;ni++)
            #pragma unroll
            for (int r=0;r<4;r++){
                float v=acc[mi][ni][r];
                if (relu) v=fmaxf(v,0.f);
                act[(mi*16+hi*4+r)*AS + colb+ni*16]=f2bf(v);
            }
}

// ---------------- combined weights -> bf16 transposed (+K=32 layer1 weights with bias folded)
__global__ void combine_weights(const float* __restrict__ sW2, const float* __restrict__ sb2,
                                const float* __restrict__ eW2, const float* __restrict__ eb2,
                                const float* __restrict__ gW1, const float* __restrict__ gb1,
                                const float* __restrict__ dW2, const float* __restrict__ gW2,
                                const float* __restrict__ oW1,
                                const float* __restrict__ eW1, const float* __restrict__ eb1,
                                const float* __restrict__ sW1, const float* __restrict__ sb1,
                                const float* __restrict__ dW1, const float* __restrict__ db1,
                                ushort* __restrict__ WT_A, ushort* __restrict__ WT_B, ushort* __restrict__ WT_E,
                                ushort* __restrict__ WT_d, ushort* __restrict__ WT_g, ushort* __restrict__ WT_o,
                                ushort* __restrict__ WT_e1, ushort* __restrict__ WT_s1, ushort* __restrict__ WT_d1,
                                float* __restrict__ bias_A, float* __restrict__ bias_B)
{
    const int j = threadIdx.x;
    const int i = blockIdx.x;   // 0..256 (256 = bias row for m<3)
    const int m = blockIdx.y;   // 0:A 1:B 2:E 3:dW2 4:gW2 5:oW1 6:e1 7:s1 8:d1
    if (m==6){ if (i<32) WT_e1[j*32+i] = f2bf(i<3 ? eW1[i*HID+j] : (i==3 ? eb1[j] : 0.f)); return; }
    if (m==7){ if (i<32) WT_s1[j*32+i] = f2bf(i<10? sW1[i*HID+j] : (i==10? sb1[j] : 0.f)); return; }
    if (m==8){ if (i<32) WT_d1[j*32+i] = f2bf(i<12? dW1[i*HID+j] : (i==12? db1[j] : 0.f)); return; }
    if (m>=3){
        if (i<HID){
            const float* S = (m==3)? dW2 : (m==4)? gW2 : oW1;
            ushort* D      = (m==3)? WT_d : (m==4)? WT_g : WT_o;
            D[j*HID+i]=f2bf(S[i*HID+j]);
        }
        return;
    }
    const float* L  = (m==2)? eW2 : sW2;
    const float* R  = gW1 + (m==0 ? HID*HID : (m==1 ? 2*HID*HID : 0));
    if (i < HID){
        float acc=0.f;
        for (int k=0;k<HID;k++) acc += L[i*HID+k]*R[k*HID+j];
        (m==0?WT_A:(m==1?WT_B:WT_E))[j*HID+i] = f2bf(acc);
    } else if (m==0){
        float acc=gb1[j];
        for (int k=0;k<HID;k++) acc += sb2[k]*gW1[(HID+k)*HID+j];
        for (int k=0;k<HID;k++) acc += eb2[k]*gW1[k*HID+j];
        bias_A[j]=acc;
    } else if (m==1){
        float acc=0.f;
        for (int k=0;k<HID;k++) acc += sb2[k]*gW1[(2*HID+k)*HID+j];
        bias_B[j]=acc;
    }
}

// ---------------- node encoder (all-MFMA): gA/gB (bf16) + h0 (bf16)
__global__ __launch_bounds__(256) void node_encode_mfma(
    const float* __restrict__ sfeat, const float* __restrict__ dfeat,
    const ushort* __restrict__ WT_s1, const ushort* __restrict__ WT_d1,
    const ushort* __restrict__ WT_d, const float* __restrict__ db2,
    const ushort* __restrict__ WT_A, const float* __restrict__ bias_A,
    const ushort* __restrict__ WT_B, const float* __restrict__ bias_B,
    ushort* __restrict__ gA, ushort* __restrict__ gB, ushort* __restrict__ h0)
{
    __shared__ ushort act[64*AS];
    __shared__ ushort A0[64*A0S];
    const int tid=threadIdx.x;
    const int n0blk=blockIdx.x*64;
    const int wv=tid>>6, lane=tid&63, n0=wv*64;
    const int rA=lane&15, kg=(lane>>4)*8, hi=lane>>4;
    const int colb=n0+rA;

    {   // stage A0 = [sfeat(10), 1, 0...]
        const int n=tid>>2, k0=(tid&3)*8;
        const int gn=n0blk+n;
        u16x8 v;
        #pragma unroll
        for (int j=0;j<8;j++){
            const int k=k0+j;
            float f = (gn<N_NODES && k<10)? sfeat[(size_t)gn*10+k] : (k==10? 1.f : 0.f);
            v[j]=f2bf(f);
        }
        *(u16x8*)&A0[n*A0S+k0]=v;
    }
    __syncthreads();
    f32x4 acc[4][4];
    {   // layer1 static: relu(A0 @ WT_s1^T)
        bf16x8 a[4], b[4];
        #pragma unroll
        for (int mi=0;mi<4;mi++) a[mi]=*(const bf16x8*)&A0[(mi*16+rA)*A0S+kg];
        #pragma unroll
        for (int ni=0;ni<4;ni++) b[ni]=*(const bf16x8*)&WT_s1[(size_t)(n0+ni*16+rA)*32+kg];
        #pragma unroll
        for (int mi=0;mi<4;mi++)
            #pragma unroll
            for (int ni=0;ni<4;ni++)
                acc[mi][ni]=mfma16(a[mi], b[ni], (f32x4){0.f,0.f,0.f,0.f});
        store_c_to_act(act, acc, colb, hi, true);
    }
    __syncthreads();
    {   // stage A0 dynamic (A0 free after gemm above)
        const int n=tid>>2, k0=(tid&3)*8;
        const int gn=n0blk+n;
        u16x8 v;
        #pragma unroll
        for (int j=0;j<8;j++){
            const int k=k0+j;
            float f = (gn<N_NODES && k<12)? dfeat[(size_t)gn*12+k] : (k==12? 1.f : 0.f);
            v[j]=f2bf(f);
        }
        *(u16x8*)&A0[n*A0S+k0]=v;
    }
    {   // gA = act @ WT_A^T + bias_A(total)
        wave_gemm(act, WT_A, n0, lane, acc);
        #pragma unroll
        for (int mi=0;mi<4;mi++){
            #pragma unroll
            for (int ni=0;ni<4;ni++){
                const int col=colb+ni*16; const float bA=bias_A[col];
                #pragma unroll
                for (int r=0;r<4;r++){
                    int rr=mi*16+hi*4+r; int gn=n0blk+rr;
                    if (gn<N_NODES) gA[(size_t)gn*HID+col]=f2bf(acc[mi][ni][r]+bA);
                }
            }
        }
    }
    {   // gB
        wave_gemm(act, WT_B, n0, lane, acc);
        #pragma unroll
        for (int mi=0;mi<4;mi++){
            #pragma unroll
            for (int ni=0;ni<4;ni++){
                const int col=colb+ni*16; const float bB=bias_B[col];
                #pragma unroll
                for (int r=0;r<4;r++){
                    int rr=mi*16+hi*4+r; int gn=n0blk+rr;
                    if (gn<N_NODES) gB[(size_t)gn*HID+col]=f2bf(acc[mi][ni][r]+bB);
                }
            }
        }
    }
    __syncthreads();   // all waves done reading act + A0d staged
    {   // layer1 dynamic: relu(A0 @ WT_d1^T)
        bf16x8 a[4], b[4];
        #pragma unroll
        for (int mi=0;mi<4;mi++) a[mi]=*(const bf16x8*)&A0[(mi*16+rA)*A0S+kg];
        #pragma unroll
        for (int ni=0;ni<4;ni++) b[ni]=*(const bf16x8*)&WT_d1[(size_t)(n0+ni*16+rA)*32+kg];
        #pragma unroll
        for (int mi=0;mi<4;mi++)
            #pragma unroll
            for (int ni=0;ni<4;ni++)
                acc[mi][ni]=mfma16(a[mi], b[ni], (f32x4){0.f,0.f,0.f,0.f});
        store_c_to_act(act, acc, colb, hi, true);
    }
    __syncthreads();
    {   // h0 = act @ WT_d^T + db2
        wave_gemm(act, WT_d, n0, lane, acc);
        #pragma unroll
        for (int mi=0;mi<4;mi++){
            #pragma unroll
            for (int ni=0;ni<4;ni++){
                const int col=colb+ni*16; const float bo=db2[col];
                #pragma unroll
                for (int r=0;r<4;r++){
                    int rr=mi*16+hi*4+r; int gn=n0blk+rr;
                    if (gn<N_NODES) h0[(size_t)gn*HID+col]=f2bf(acc[mi][ni][r]+bo);
                }
            }
        }
    }
}

// ---------------- edge encoder: all-MFMA, CSR-slot order, reg-prefetched gA, per-wave fused remap
__global__ __launch_bounds__(256) void edge_encode_mfma(
    const float* __restrict__ eattr, const int* __restrict__ eidx,
    const int* __restrict__ csr_src, const int* __restrict__ csr_eid,
    const ushort* __restrict__ WT_e1,
    const ushort* __restrict__ WT_E,
    const ushort* __restrict__ WT_g2, const float* __restrict__ gb2,
    const ushort* __restrict__ gA, const ushort* __restrict__ gB,
    ushort* __restrict__ g_out)
{
    __shared__ ushort act[64*AS];
    __shared__ ushort A0[64*A0S];
    __shared__ int si[64], di[64], ei[64];
    const int tid=threadIdx.x;
    // XCD-aware swizzle: grid = 4688 = 8*586 exactly -> simple bijective form
    const int bid=blockIdx.x;
    const int s0=((bid&7)*586 + (bid>>3))*64;
    const int wv=tid>>6, lane=tid&63, n0=wv*64;
    const int rA=lane&15, kg=(lane>>4)*8, hi=lane>>4;
    const int colb=n0+rA;

    if (tid<64){
        int s=s0+tid; bool v=s<N_EDGES;
        int eid=v? csr_eid[s]:0;
        si[tid]=v? csr_src[s]:0;
        di[tid]=v? eidx[N_EDGES+eid]:0;
        ei[tid]=eid;
    }
    __syncthreads();
    // prefetch gA[si[lane]] row-slice (this wave's 64 cols), rotated 16B blocks: held ~2 phases
    u16x8 gpa[8];
    {
        const ushort* garow=&gA[(size_t)si[lane]*HID + n0];
        #pragma unroll
        for (int j=0;j<8;j++)
            gpa[j]=*(const u16x8*)&garow[((j+lane)&7)*8];
    }
    {   // stage A0 = [eattr(3), 1, 0...]
        const int n=tid>>2, k0=(tid&3)*8;
        const int eid=ei[n];
        u16x8 v;
        #pragma unroll
        for (int j=0;j<8;j++){
            const int k=k0+j;
            float f = (k<3)? eattr[(size_t)eid*3+k] : (k==3? 1.f : 0.f);
            v[j]=f2bf(f);
        }
        *(u16x8*)&A0[n*A0S+k0]=v;
    }
    __syncthreads();
    f32x4 acc[4][4];
    {   // gemm0: e1 = relu(A0 @ WT_e1^T), K=32
        bf16x8 a[4], b[4];
        #pragma unroll
        for (int mi=0;mi<4;mi++) a[mi]=*(const bf16x8*)&A0[(mi*16+rA)*A0S+kg];
        #pragma unroll
        for (int ni=0;ni<4;ni++) b[ni]=*(const bf16x8*)&WT_e1[(size_t)(n0+ni*16+rA)*32+kg];
        #pragma unroll
        for (int mi=0;mi<4;mi++)
            #pragma unroll
            for (int ni=0;ni<4;ni++)
                acc[mi][ni]=mfma16(a[mi], b[ni], (f32x4){0.f,0.f,0.f,0.f});
        store_c_to_act(act, acc, colb, hi, true);
    }
    __syncthreads();
    wave_gemm(act, WT_E, n0, lane, acc);    // gemm1
    __syncthreads();                        // all waves done reading act
    store_c_to_act(act, acc, colb, hi, false);  // raw acc1 into own col-slice
    {   // fused remap (same wave, same col-slice; intra-wave lgkm dep only):
        // act[lane][n0..n0+64) = relu(act + gpa + gB[di[lane]])
        const ushort* gbrow=&gB[(size_t)di[lane]*HID + n0];
        ushort* arow=&act[lane*AS + n0];
        #pragma unroll
        for (int j=0;j<8;j++){
            const int jb=((j+lane)&7)*8;
            u16x8 av=*(u16x8*)&arow[jb];
            u16x8 gb=*(const u16x8*)&gbrow[jb];
            u16x8 o;
            #pragma unroll
            for (int q=0;q<8;q++)
                o[q]=f2bf(fmaxf(bf2f(av[q])+bf2f(gpa[j][q])+bf2f(gb[q]),0.f));
            *(u16x8*)&arow[jb]=o;
        }
    }
    __syncthreads();
    wave_gemm(act, WT_g2, n0, lane, acc);   // gemm2
    {   // epilogue: + gb2 -> g_out[slot] (C-layout direct stores)
        #pragma unroll
        for (int mi=0;mi<4;mi++){
            #pragma unroll
            for (int ni=0;ni<4;ni++){
                const int col=colb+ni*16; const float bg=gb2[col];
                #pragma unroll
                for (int r=0;r<4;r++){
                    const int rr=mi*16+hi*4+r;
                    if (s0+rr<N_EDGES)
                        g_out[(size_t)(s0+rr)*HID+col]=f2bf(acc[mi][ni][r]+bg);
                }
            }
        }
    }
}

// ---------------- CSR build
__global__ void deg_count(const int* __restrict__ eidx, uint* __restrict__ deg){
    int e=blockIdx.x*blockDim.x+threadIdx.x;
    if (e<N_EDGES) atomicAdd(&deg[eidx[N_EDGES+e]],1u);
}

__global__ void scan_kernel(const uint* __restrict__ deg, uint* __restrict__ row_start){
    __shared__ uint wtot[16];
    __shared__ uint woff[17];
    __shared__ uint carry_s;
    const int tid=threadIdx.x, lane=tid&63, wid=tid>>6;
    if (tid==0) carry_s=0;
    __syncthreads();
    for (uint base=0; base<N_NODES; base+=1024){
        uint idx=base+tid;
        uint v=(idx<N_NODES)? deg[idx]:0u;
        uint s=v;
        #pragma unroll
        for (int d=1; d<64; d<<=1){
            uint t=__shfl_up(s,d,64);
            if (lane>=d) s+=t;
        }
        if (lane==63) wtot[wid]=s;
        __syncthreads();
        if (tid==0){ uint r=0; for (int i=0;i<16;i++){ woff[i]=r; r+=wtot[i]; } woff[16]=r; }
        __syncthreads();
        uint excl = carry_s + woff[wid] + s - v;
        if (idx<N_NODES) row_start[idx]=excl;
        __syncthreads();
        if (tid==0) carry_s += woff[16];
        __syncthreads();
    }
}

__global__ void csr_fill(const int* __restrict__ eidx, const uint* __restrict__ row_start,
                         uint* __restrict__ cursor, int* __restrict__ csr_src, int* __restrict__ csr_eid){
    int e=blockIdx.x*blockDim.x+threadIdx.x;
    if (e>=N_EDGES) return;
    int d=eidx[N_EDGES+e];
    uint pos=atomicAdd(&cursor[d],1u);
    uint s=row_start[d]+pos;
    csr_src[s]=eidx[e];
    csr_eid[s]=e;
}

// ---------------- message-passing hop: one wave per node, CSR gather, bf16 h in/out
__global__ __launch_bounds__(256) void hop_kernel(
    const ushort* __restrict__ h_in, ushort* __restrict__ h_out,
    const ushort* __restrict__ g, const int* __restrict__ csr_src,
    const uint* __restrict__ row_start, const uint* __restrict__ deg)
{
    const int gw=(blockIdx.x*blockDim.x+threadIdx.x)>>6;
    if (gw>=N_NODES) return;
    const int c0=(threadIdx.x&63)*4;
    ushort4 hd4=*(const ushort4*)&h_in[(size_t)gw*HID+c0];
    float4 hd; hd.x=bf2f(hd4.x); hd.y=bf2f(hd4.y); hd.z=bf2f(hd4.z); hd.w=bf2f(hd4.w);
    float4 acc=make_float4(0,0,0,0);
    const uint st=row_start[gw], len=deg[gw];
    for (uint u=0;u<len;u++){
        uint s=st+u;
        int sn=csr_src[s];
        ushort4 g4=*(const ushort4*)&g[(size_t)s*HID+c0];
        ushort4 hs4=*(const ushort4*)&h_in[(size_t)sn*HID+c0];
        acc.x += bf2f(g4.x)*(bf2f(hs4.x)-hd.x);
        acc.y += bf2f(g4.y)*(bf2f(hs4.y)-hd.y);
        acc.z += bf2f(g4.z)*(bf2f(hs4.z)-hd.z);
        acc.w += bf2f(g4.w)*(bf2f(hs4.w)-hd.w);
    }
    const float inv=1.f/fmaxf((float)len,1.f);
    ushort4 o; o.x=f2bf(hd.x+acc.x*inv); o.y=f2bf(hd.y+acc.y*inv);
               o.z=f2bf(hd.z+acc.z*inv); o.w=f2bf(hd.w+acc.w*inv);
    *(ushort4*)&h_out[(size_t)gw*HID+c0]=o;
}

// ---------------- decoder (MFMA): out = relu(tanh(h)@oW1+ob1)@oW2+ob2
__global__ __launch_bounds__(256) void decoder_mfma(
    const ushort* __restrict__ h, const ushort* __restrict__ WT_o,
    const float* __restrict__ ob1, const float* __restrict__ oW2, const float* __restrict__ ob2,
    float* __restrict__ out)
{
    __shared__ ushort act[64*AS];
    const int tid=threadIdx.x, n0blk=blockIdx.x*64;
    const int wv=tid>>6, lane=tid&63, n0=wv*64, colb=n0+(lane&15);
    {   // stage tanh(h) -> act (bf16)
        const int row=tid>>2, cc=(tid&3)*64;
        const int gn=n0blk+row;
        #pragma unroll
        for (int k=0;k<64;k+=8){
            u16x8 t;
            if (gn<N_NODES){
                u16x8 v=*(const u16x8*)&h[(size_t)gn*HID+cc+k];
                #pragma unroll
                for (int j=0;j<8;j++) t[j]=f2bf(tanhf(bf2f(v[j])));
            } else {
                #pragma unroll
                for (int j=0;j<8;j++) t[j]=0;
            }
            *(u16x8*)&act[row*AS+cc+k]=t;
        }
    }
    __syncthreads();
    f32x4 acc[4][4];
    wave_gemm(act, WT_o, n0, lane, acc);
    __syncthreads();
    #pragma unroll
    for (int mi=0;mi<4;mi++){
        #pragma unroll
        for (int ni=0;ni<4;ni++){
            const int col=colb+ni*16; const float b1=ob1[col];
            #pragma unroll
            for (int r=0;r<4;r++){
                const int rr=mi*16+(lane>>4)*4+r;
                act[rr*AS+col]=f2bf(fmaxf(acc[mi][ni][r]+b1,0.f));
            }
        }
    }
    __syncthreads();
    if (tid<192){
        const int n=tid/3, o=tid-n*3;
        float a=ob2[o];
        for (int k=0;k<HID;k++) a+=bf2f(act[n*AS+k])*oW2[k*3+o];
        const int gn=n0blk+n;
        if (gn<N_NODES) out[(size_t)gn*3+o]=a;
    }
}

extern "C" void kernel_launch(void* const* d_in, const int* in_sizes, int n_in,
                              void* d_out, int out_size, void* d_ws, size_t ws_size,
                              hipStream_t stream)
{
    (void)in_sizes; (void)n_in; (void)out_size;
    const float* sfeat=(const float*)d_in[0];
    const float* dfeat=(const float*)d_in[1];
    const int*   eidx =(const int*)  d_in[2];
    const float* eattr=(const float*)d_in[3];
    const float* sW1=(const float*)d_in[4];  const float* sb1=(const float*)d_in[5];
    const float* sW2=(const float*)d_in[6];  const float* sb2=(const float*)d_in[7];
    const float* dW1=(const float*)d_in[8];  const float* db1=(const float*)d_in[9];
    const float* dW2=(const float*)d_in[10]; const float* db2=(const float*)d_in[11];
    const float* eW1=(const float*)d_in[12]; const float* eb1=(const float*)d_in[13];
    const float* eW2=(const float*)d_in[14]; const float* eb2=(const float*)d_in[15];
    const float* gW1=(const float*)d_in[16]; const float* gb1=(const float*)d_in[17];
    const float* gW2=(const float*)d_in[18]; const float* gb2=(const float*)d_in[19];
    const float* oW1=(const float*)d_in[20]; const float* ob1=(const float*)d_in[21];
    const float* oW2=(const float*)d_in[22]; const float* ob2=(const float*)d_in[23];
    float* out=(float*)d_out;

    char* p=(char*)d_ws;
    size_t used=0;
    auto alloc=[&](size_t bytes)->char*{
        char* r=p+used; used += (bytes+255)&~(size_t)255; return r;
    };
    ushort* WT_A=(ushort*)alloc(HID*HID*2);
    ushort* WT_B=(ushort*)alloc(HID*HID*2);
    ushort* WT_E=(ushort*)alloc(HID*HID*2);
    ushort* WT_d=(ushort*)alloc(HID*HID*2);
    ushort* WT_g=(ushort*)alloc(HID*HID*2);
    ushort* WT_o=(ushort*)alloc(HID*HID*2);
    ushort* WT_e1=(ushort*)alloc(HID*32*2);
    ushort* WT_s1=(ushort*)alloc(HID*32*2);
    ushort* WT_d1=(ushort*)alloc(HID*32*2);
    float* bias_A=(float*)alloc(HID*4);
    float* bias_B=(float*)alloc(HID*4);
    ushort* gA=(ushort*)alloc((size_t)N_NODES*HID*2);
    ushort* gB=(ushort*)alloc((size_t)N_NODES*HID*2);
    ushort* g =(ushort*)alloc((size_t)N_EDGES*HID*2);
    ushort* h0=(ushort*)alloc((size_t)N_NODES*HID*2);
    uint* deg      =(uint*)alloc(N_NODES*4);
    uint* row_start=(uint*)alloc(N_NODES*4);
    uint* cursor   =(uint*)alloc(N_NODES*4);
    int* csr_src=(int*)alloc(N_EDGES*4);
    int* csr_eid=(int*)alloc(N_EDGES*4);
    ushort* h1=gA;   // alias: gA/gB dead after edge_encode

    if (used > ws_size) return;  // clean fail if ws too small

    hipMemsetAsync(deg, 0, N_NODES*4, stream);
    hipMemsetAsync(cursor, 0, N_NODES*4, stream);

    combine_weights<<<dim3(HID+1,9),256,0,stream>>>(sW2,sb2,eW2,eb2,gW1,gb1,dW2,gW2,oW1,eW1,eb1,sW1,sb1,dW1,db1,
                                                    WT_A,WT_B,WT_E,WT_d,WT_g,WT_o,WT_e1,WT_s1,WT_d1,bias_A,bias_B);
    node_encode_mfma<<<(N_NODES+63)/64,256,0,stream>>>(sfeat,dfeat,WT_s1,WT_d1,WT_d,db2,WT_A,bias_A,WT_B,bias_B,gA,gB,h0);
    deg_count<<<(N_EDGES+255)/256,256,0,stream>>>(eidx,deg);
    scan_kernel<<<1,1024,0,stream>>>(deg,row_start);
    csr_fill<<<(N_EDGES+255)/256,256,0,stream>>>(eidx,row_start,cursor,csr_src,csr_eid);
    edge_encode_mfma<<<(N_EDGES+63)/64,256,0,stream>>>(eattr,eidx,csr_src,csr_eid,WT_e1,WT_E,WT_g,gb2,gA,gB,g);
    hop_kernel<<<N_NODES/4,256,0,stream>>>(h0,h1,g,csr_src,row_start,deg);
    hop_kernel<<<N_NODES/4,256,0,stream>>>(h1,h0,g,csr_src,row_start,deg);
    decoder_mfma<<<(N_NODES+63)/64,256,0,stream>>>(h0,WT_o,ob1,oW2,ob2,out);
}

// Round 8
// 581.040 us; speedup vs baseline: 2.7379x; 1.0187x over previous
//
#include <hip/hip_runtime.h>
#include <hip/hip_bf16.h>

#define N_NODES 50000
#define N_EDGES 300000
#define HID 256
#define AS 264      // LDS act stride in bf16 elems: 264*2=528B = 33*16 -> 16B-aligned rows
#define A0S 40      // A0 stride (ushorts): 80B rows, 16B-aligned

typedef unsigned int uint;
typedef unsigned short ushort;
typedef short bf16x8 __attribute__((ext_vector_type(8)));
typedef unsigned short u16x8 __attribute__((ext_vector_type(8)));
typedef float f32x4 __attribute__((ext_vector_type(4)));

__device__ __forceinline__ float bf2f(ushort u){ union{uint i; float f;} v; v.i=((uint)u)<<16; return v.f; }
__device__ __forceinline__ ushort f2bf(float f){ __hip_bfloat16 h=__float2bfloat16(f); return *reinterpret_cast<ushort*>(&h); }

__device__ __forceinline__ f32x4 mfma16(bf16x8 a, bf16x8 b, f32x4 c){
    return __builtin_amdgcn_mfma_f32_16x16x32_bf16(a, b, c, 0, 0, 0);
}

// wave computes rows 0..63 of act (LDS, row-major stride AS) x cols [n0,n0+64) of WT (bf16 [N][K=256])
__device__ __forceinline__ void wave_gemm(const ushort* act, const ushort* __restrict__ WT,
                                          int n0, int lane, f32x4 acc[4][4])
{
    #pragma unroll
    for (int mi=0;mi<4;mi++)
        #pragma unroll
        for (int ni=0;ni<4;ni++) acc[mi][ni]=(f32x4){0.f,0.f,0.f,0.f};
    const int rA=lane&15, kg=(lane>>4)*8;
    #pragma unroll
    for (int kk=0;kk<8;kk++){
        const int ka=kk*32+kg;
        bf16x8 a[4], b[4];
        #pragma unroll
        for (int mi=0;mi<4;mi++) a[mi]=*(const bf16x8*)&act[(mi*16+rA)*AS+ka];
        #pragma unroll
        for (int ni=0;ni<4;ni++) b[ni]=*(const bf16x8*)&WT[(size_t)((n0+ni*16+rA)*HID+ka)];
        #pragma unroll
        for (int mi=0;mi<4;mi++)
            #pragma unroll
            for (int ni=0;ni<4;ni++)
                acc[mi][ni]=mfma16(a[mi], b[ni], acc[mi][ni]);
    }
}

// scatter C-layout accumulator into act LDS (scalar b16 writes), optional relu
__device__ __forceinline__ void store_c_to_act(ushort* act, const f32x4 acc[4][4],
                                               int colb, int hi, bool relu)
{
    #pragma unroll
    for (int mi=0;mi<4;mi++)
        #pragma unroll
        for (int ni=0;ni<4;ni++)
            #pragma unroll
            for (int r=0;r<4;r++){
                float v=acc[mi][ni][r];
                if (relu) v=fmaxf(v,0.f);
                act[(mi*16+hi*4+r)*AS + colb+ni*16]=f2bf(v);
            }
}

// ---------------- combined weights -> bf16 transposed (+K=32 layer1 weights with bias folded)
__global__ void combine_weights(const float* __restrict__ sW2, const float* __restrict__ sb2,
                                const float* __restrict__ eW2, const float* __restrict__ eb2,
                                const float* __restrict__ gW1, const float* __restrict__ gb1,
                                const float* __restrict__ dW2, const float* __restrict__ gW2,
                                const float* __restrict__ oW1,
                                const float* __restrict__ eW1, const float* __restrict__ eb1,
                                const float* __restrict__ sW1, const float* __restrict__ sb1,
                                const float* __restrict__ dW1, const float* __restrict__ db1,
                                ushort* __restrict__ WT_A, ushort* __restrict__ WT_B, ushort* __restrict__ WT_E,
                                ushort* __restrict__ WT_d, ushort* __restrict__ WT_g, ushort* __restrict__ WT_o,
                                ushort* __restrict__ WT_e1, ushort* __restrict__ WT_s1, ushort* __restrict__ WT_d1,
                                float* __restrict__ bias_A, float* __restrict__ bias_B)
{
    const int j = threadIdx.x;
    const int i = blockIdx.x;   // 0..256 (256 = bias row for m<3)
    const int m = blockIdx.y;   // 0:A 1:B 2:E 3:dW2 4:gW2 5:oW1 6:e1 7:s1 8:d1
    if (m==6){ if (i<32) WT_e1[j*32+i] = f2bf(i<3 ? eW1[i*HID+j] : (i==3 ? eb1[j] : 0.f)); return; }
    if (m==7){ if (i<32) WT_s1[j*32+i] = f2bf(i<10? sW1[i*HID+j] : (i==10? sb1[j] : 0.f)); return; }
    if (m==8){ if (i<32) WT_d1[j*32+i] = f2bf(i<12? dW1[i*HID+j] : (i==12? db1[j] : 0.f)); return; }
    if (m>=3){
        if (i<HID){
            const float* S = (m==3)? dW2 : (m==4)? gW2 : oW1;
            ushort* D      = (m==3)? WT_d : (m==4)? WT_g : WT_o;
            D[j*HID+i]=f2bf(S[i*HID+j]);
        }
        return;
    }
    const float* L  = (m==2)? eW2 : sW2;
    const float* R  = gW1 + (m==0 ? HID*HID : (m==1 ? 2*HID*HID : 0));
    if (i < HID){
        float acc=0.f;
        for (int k=0;k<HID;k++) acc += L[i*HID+k]*R[k*HID+j];
        (m==0?WT_A:(m==1?WT_B:WT_E))[j*HID+i] = f2bf(acc);
    } else if (m==0){
        float acc=gb1[j];
        for (int k=0;k<HID;k++) acc += sb2[k]*gW1[(HID+k)*HID+j];
        for (int k=0;k<HID;k++) acc += eb2[k]*gW1[k*HID+j];
        bias_A[j]=acc;
    } else if (m==1){
        float acc=0.f;
        for (int k=0;k<HID;k++) acc += sb2[k]*gW1[(2*HID+k)*HID+j];
        bias_B[j]=acc;
    }
}

// ---------------- node encoder (all-MFMA): gA/gB (bf16) + h0 (bf16)
__global__ __launch_bounds__(256) void node_encode_mfma(
    const float* __restrict__ sfeat, const float* __restrict__ dfeat,
    const ushort* __restrict__ WT_s1, const ushort* __restrict__ WT_d1,
    const ushort* __restrict__ WT_d, const float* __restrict__ db2,
    const ushort* __restrict__ WT_A, const float* __restrict__ bias_A,
    const ushort* __restrict__ WT_B, const float* __restrict__ bias_B,
    ushort* __restrict__ gA, ushort* __restrict__ gB, ushort* __restrict__ h0)
{
    __shared__ ushort act[64*AS];
    __shared__ ushort A0[64*A0S];
    const int tid=threadIdx.x;
    const int n0blk=blockIdx.x*64;
    const int wv=tid>>6, lane=tid&63, n0=wv*64;
    const int rA=lane&15, kg=(lane>>4)*8, hi=lane>>4;
    const int colb=n0+rA;

    {   // stage A0 = [sfeat(10), 1, 0...]
        const int n=tid>>2, k0=(tid&3)*8;
        const int gn=n0blk+n;
        u16x8 v;
        #pragma unroll
        for (int j=0;j<8;j++){
            const int k=k0+j;
            float f = (gn<N_NODES && k<10)? sfeat[(size_t)gn*10+k] : (k==10? 1.f : 0.f);
            v[j]=f2bf(f);
        }
        *(u16x8*)&A0[n*A0S+k0]=v;
    }
    __syncthreads();
    f32x4 acc[4][4];
    {   // layer1 static: relu(A0 @ WT_s1^T)
        bf16x8 a[4], b[4];
        #pragma unroll
        for (int mi=0;mi<4;mi++) a[mi]=*(const bf16x8*)&A0[(mi*16+rA)*A0S+kg];
        #pragma unroll
        for (int ni=0;ni<4;ni++) b[ni]=*(const bf16x8*)&WT_s1[(size_t)(n0+ni*16+rA)*32+kg];
        #pragma unroll
        for (int mi=0;mi<4;mi++)
            #pragma unroll
            for (int ni=0;ni<4;ni++)
                acc[mi][ni]=mfma16(a[mi], b[ni], (f32x4){0.f,0.f,0.f,0.f});
        store_c_to_act(act, acc, colb, hi, true);
    }
    __syncthreads();
    {   // stage A0 dynamic (A0 free after gemm above)
        const int n=tid>>2, k0=(tid&3)*8;
        const int gn=n0blk+n;
        u16x8 v;
        #pragma unroll
        for (int j=0;j<8;j++){
            const int k=k0+j;
            float f = (gn<N_NODES && k<12)? dfeat[(size_t)gn*12+k] : (k==12? 1.f : 0.f);
            v[j]=f2bf(f);
        }
        *(u16x8*)&A0[n*A0S+k0]=v;
    }
    {   // gA = act @ WT_A^T + bias_A(total)
        wave_gemm(act, WT_A, n0, lane, acc);
        #pragma unroll
        for (int mi=0;mi<4;mi++){
            #pragma unroll
            for (int ni=0;ni<4;ni++){
                const int col=colb+ni*16; const float bA=bias_A[col];
                #pragma unroll
                for (int r=0;r<4;r++){
                    int rr=mi*16+hi*4+r; int gn=n0blk+rr;
                    if (gn<N_NODES) gA[(size_t)gn*HID+col]=f2bf(acc[mi][ni][r]+bA);
                }
            }
        }
    }
    {   // gB
        wave_gemm(act, WT_B, n0, lane, acc);
        #pragma unroll
        for (int mi=0;mi<4;mi++){
            #pragma unroll
            for (int ni=0;ni<4;ni++){
                const int col=colb+ni*16; const float bB=bias_B[col];
                #pragma unroll
                for (int r=0;r<4;r++){
                    int rr=mi*16+hi*4+r; int gn=n0blk+rr;
                    if (gn<N_NODES) gB[(size_t)gn*HID+col]=f2bf(acc[mi][ni][r]+bB);
                }
            }
        }
    }
    __syncthreads();   // all waves done reading act + A0d staged
    {   // layer1 dynamic: relu(A0 @ WT_d1^T)
        bf16x8 a[4], b[4];
        #pragma unroll
        for (int mi=0;mi<4;mi++) a[mi]=*(const bf16x8*)&A0[(mi*16+rA)*A0S+kg];
        #pragma unroll
        for (int ni=0;ni<4;ni++) b[ni]=*(const bf16x8*)&WT_d1[(size_t)(n0+ni*16+rA)*32+kg];
        #pragma unroll
        for (int mi=0;mi<4;mi++)
            #pragma unroll
            for (int ni=0;ni<4;ni++)
                acc[mi][ni]=mfma16(a[mi], b[ni], (f32x4){0.f,0.f,0.f,0.f});
        store_c_to_act(act, acc, colb, hi, true);
    }
    __syncthreads();
    {   // h0 = act @ WT_d^T + db2
        wave_gemm(act, WT_d, n0, lane, acc);
        #pragma unroll
        for (int mi=0;mi<4;mi++){
            #pragma unroll
            for (int ni=0;ni<4;ni++){
                const int col=colb+ni*16; const float bo=db2[col];
                #pragma unroll
                for (int r=0;r<4;r++){
                    int rr=mi*16+hi*4+r; int gn=n0blk+rr;
                    if (gn<N_NODES) h0[(size_t)gn*HID+col]=f2bf(acc[mi][ni][r]+bo);
                }
            }
        }
    }
}

// ---------------- edge encoder: 128-edge tile, 8 waves (2M x 4N), all-MFMA, CSR-slot order
__global__ __launch_bounds__(512) void edge_encode_mfma(
    const float* __restrict__ eattr, const int* __restrict__ eidx,
    const int* __restrict__ csr_src, const int* __restrict__ csr_eid,
    const ushort* __restrict__ WT_e1,
    const ushort* __restrict__ WT_E,
    const ushort* __restrict__ WT_g2, const float* __restrict__ gb2,
    const ushort* __restrict__ gA, const ushort* __restrict__ gB,
    ushort* __restrict__ g_out)
{
    __shared__ ushort act[128*AS];    // 67.6 KB
    __shared__ ushort A0[128*A0S];    // 10.25 KB
    __shared__ int si[128], di[128], ei[128];
    const int tid=threadIdx.x;
    // XCD-aware swizzle: grid = 2344 = 8*293 exactly -> bijective
    const int bid=blockIdx.x;
    const int s0=((bid&7)*293 + (bid>>3))*128;
    const int wv=tid>>6, lane=tid&63;
    const int wm=wv>>2, wn=wv&3;          // 2M x 4N wave grid
    const int m0=wm*64, n0=wn*64;
    const int rA=lane&15, kg=(lane>>4)*8, hi=lane>>4;
    const int colb=n0+rA;

    if (tid<128){
        int s=s0+tid; bool v=s<N_EDGES;
        int eid=v? csr_eid[s]:0;
        si[tid]=v? csr_src[s]:0;
        di[tid]=v? eidx[N_EDGES+eid]:0;
        ei[tid]=eid;
    }
    __syncthreads();
    {   // stage A0 = [eattr(3), 1, 0...]  (4 threads per row)
        const int n=tid>>2, k0=(tid&3)*8;
        const int eid=ei[n];
        u16x8 v;
        #pragma unroll
        for (int j=0;j<8;j++){
            const int k=k0+j;
            float f = (k<3)? eattr[(size_t)eid*3+k] : (k==3? 1.f : 0.f);
            v[j]=f2bf(f);
        }
        *(u16x8*)&A0[n*A0S+k0]=v;
    }
    __syncthreads();
    f32x4 acc[4][4];
    {   // gemm0: e1 = relu(A0 @ WT_e1^T), K=32, rows m0..m0+63
        bf16x8 a[4], b[4];
        #pragma unroll
        for (int mi=0;mi<4;mi++) a[mi]=*(const bf16x8*)&A0[(m0+mi*16+rA)*A0S+kg];
        #pragma unroll
        for (int ni=0;ni<4;ni++) b[ni]=*(const bf16x8*)&WT_e1[(size_t)(n0+ni*16+rA)*32+kg];
        #pragma unroll
        for (int mi=0;mi<4;mi++)
            #pragma unroll
            for (int ni=0;ni<4;ni++)
                acc[mi][ni]=mfma16(a[mi], b[ni], (f32x4){0.f,0.f,0.f,0.f});
        store_c_to_act(act + m0*AS, acc, colb, hi, true);
    }
    __syncthreads();
    wave_gemm(act + m0*AS, WT_E, n0, lane, acc);   // gemm1 on own 64-row group
    __syncthreads();                               // all waves done reading act
    store_c_to_act(act + m0*AS, acc, colb, hi, false);   // raw acc1 into own 64x64 patch
    {   // fused remap of own patch (intra-wave dep only):
        // act[m0+lane][n0..n0+64) = relu(acc1 + gA[src] + gB[dst])
        const int row=m0+lane;
        const ushort* garow=&gA[(size_t)si[row]*HID + n0];
        const ushort* gbrow=&gB[(size_t)di[row]*HID + n0];
        ushort* arow=&act[row*AS + n0];
        #pragma unroll
        for (int j=0;j<8;j++){
            const int jb=((j+lane)&7)*8;
            u16x8 av=*(u16x8*)&arow[jb];
            u16x8 ga=*(const u16x8*)&garow[jb];
            u16x8 gb=*(const u16x8*)&gbrow[jb];
            u16x8 o;
            #pragma unroll
            for (int q=0;q<8;q++)
                o[q]=f2bf(fmaxf(bf2f(av[q])+bf2f(ga[q])+bf2f(gb[q]),0.f));
            *(u16x8*)&arow[jb]=o;
        }
    }
    __syncthreads();
    wave_gemm(act + m0*AS, WT_g2, n0, lane, acc);  // gemm2
    {   // epilogue: + gb2 -> g_out[slot] (C-layout direct stores)
        #pragma unroll
        for (int mi=0;mi<4;mi++){
            #pragma unroll
            for (int ni=0;ni<4;ni++){
                const int col=colb+ni*16; const float bg=gb2[col];
                #pragma unroll
                for (int r=0;r<4;r++){
                    const int rr=m0+mi*16+hi*4+r;
                    if (s0+rr<N_EDGES)
                        g_out[(size_t)(s0+rr)*HID+col]=f2bf(acc[mi][ni][r]+bg);
                }
            }
        }
    }
}

// ---------------- CSR build
__global__ void deg_count(const int* __restrict__ eidx, uint* __restrict__ deg){
    int e=blockIdx.x*blockDim.x+threadIdx.x;
    if (e<N_EDGES) atomicAdd(&deg[eidx[N_EDGES+e]],1u);
}

__global__ void scan_kernel(const uint* __restrict__ deg, uint* __restrict__ row_start){
    __shared__ uint wtot[16];
    __shared__ uint woff[17];
    __shared__ uint carry_s;
    const int tid=threadIdx.x, lane=tid&63, wid=tid>>6;
    if (tid==0) carry_s=0;
    __syncthreads();
    for (uint base=0; base<N_NODES; base+=1024){
        uint idx=base+tid;
        uint v=(idx<N_NODES)? deg[idx]:0u;
        uint s=v;
        #pragma unroll
        for (int d=1; d<64; d<<=1){
            uint t=__shfl_up(s,d,64);
            if (lane>=d) s+=t;
        }
        if (lane==63) wtot[wid]=s;
        __syncthreads();
        if (tid==0){ uint r=0; for (int i=0;i<16;i++){ woff[i]=r; r+=wtot[i]; } woff[16]=r; }
        __syncthreads();
        uint excl = carry_s + woff[wid] + s - v;
        if (idx<N_NODES) row_start[idx]=excl;
        __syncthreads();
        if (tid==0) carry_s += woff[16];
        __syncthreads();
    }
}

__global__ void csr_fill(const int* __restrict__ eidx, const uint* __restrict__ row_start,
                         uint* __restrict__ cursor, int* __restrict__ csr_src, int* __restrict__ csr_eid){
    int e=blockIdx.x*blockDim.x+threadIdx.x;
    if (e>=N_EDGES) return;
    int d=eidx[N_EDGES+e];
    uint pos=atomicAdd(&cursor[d],1u);
    uint s=row_start[d]+pos;
    csr_src[s]=eidx[e];
    csr_eid[s]=e;
}

// ---------------- message-passing hop: one wave per node, CSR gather, bf16 h in/out
__global__ __launch_bounds__(256) void hop_kernel(
    const ushort* __restrict__ h_in, ushort* __restrict__ h_out,
    const ushort* __restrict__ g, const int* __restrict__ csr_src,
    const uint* __restrict__ row_start, const uint* __restrict__ deg)
{
    const int gw=(blockIdx.x*blockDim.x+threadIdx.x)>>6;
    if (gw>=N_NODES) return;
    const int c0=(threadIdx.x&63)*4;
    ushort4 hd4=*(const ushort4*)&h_in[(size_t)gw*HID+c0];
    float4 hd; hd.x=bf2f(hd4.x); hd.y=bf2f(hd4.y); hd.z=bf2f(hd4.z); hd.w=bf2f(hd4.w);
    float4 acc=make_float4(0,0,0,0);
    const uint st=row_start[gw], len=deg[gw];
    for (uint u=0;u<len;u++){
        uint s=st+u;
        int sn=csr_src[s];
        ushort4 g4=*(const ushort4*)&g[(size_t)s*HID+c0];
        ushort4 hs4=*(const ushort4*)&h_in[(size_t)sn*HID+c0];
        acc.x += bf2f(g4.x)*(bf2f(hs4.x)-hd.x);
        acc.y += bf2f(g4.y)*(bf2f(hs4.y)-hd.y);
        acc.z += bf2f(g4.z)*(bf2f(hs4.z)-hd.z);
        acc.w += bf2f(g4.w)*(bf2f(hs4.w)-hd.w);
    }
    const float inv=1.f/fmaxf((float)len,1.f);
    ushort4 o; o.x=f2bf(hd.x+acc.x*inv); o.y=f2bf(hd.y+acc.y*inv);
               o.z=f2bf(hd.z+acc.z*inv); o.w=f2bf(hd.w+acc.w*inv);
    *(ushort4*)&h_out[(size_t)gw*HID+c0]=o;
}

// ---------------- decoder (MFMA): out = relu(tanh(h)@oW1+ob1)@oW2+ob2
__global__ __launch_bounds__(256) void decoder_mfma(
    const ushort* __restrict__ h, const ushort* __restrict__ WT_o,
    const float* __restrict__ ob1, const float* __restrict__ oW2, const float* __restrict__ ob2,
    float* __restrict__ out)
{
    __shared__ ushort act[64*AS];
    const int tid=threadIdx.x, n0blk=blockIdx.x*64;
    const int wv=tid>>6, lane=tid&63, n0=wv*64, colb=n0+(lane&15);
    {   // stage tanh(h) -> act (bf16)
        const int row=tid>>2, cc=(tid&3)*64;
        const int gn=n0blk+row;
        #pragma unroll
        for (int k=0;k<64;k+=8){
            u16x8 t;
            if (gn<N_NODES){
                u16x8 v=*(const u16x8*)&h[(size_t)gn*HID+cc+k];
                #pragma unroll
                for (int j=0;j<8;j++) t[j]=f2bf(tanhf(bf2f(v[j])));
            } else {
                #pragma unroll
                for (int j=0;j<8;j++) t[j]=0;
            }
            *(u16x8*)&act[row*AS+cc+k]=t;
        }
    }
    __syncthreads();
    f32x4 acc[4][4];
    wave_gemm(act, WT_o, n0, lane, acc);
    __syncthreads();
    #pragma unroll
    for (int mi=0;mi<4;mi++){
        #pragma unroll
        for (int ni=0;ni<4;ni++){
            const int col=colb+ni*16; const float b1=ob1[col];
            #pragma unroll
            for (int r=0;r<4;r++){
                const int rr=mi*16+(lane>>4)*4+r;
                act[rr*AS+col]=f2bf(fmaxf(acc[mi][ni][r]+b1,0.f));
            }
        }
    }
    __syncthreads();
    if (tid<192){
        const int n=tid/3, o=tid-n*3;
        float a=ob2[o];
        for (int k=0;k<HID;k++) a+=bf2f(act[n*AS+k])*oW2[k*3+o];
        const int gn=n0blk+n;
        if (gn<N_NODES) out[(size_t)gn*3+o]=a;
    }
}

extern "C" void kernel_launch(void* const* d_in, const int* in_sizes, int n_in,
                              void* d_out, int out_size, void* d_ws, size_t ws_size,
                              hipStream_t stream)
{
    (void)in_sizes; (void)n_in; (void)out_size;
    const float* sfeat=(const float*)d_in[0];
    const float* dfeat=(const float*)d_in[1];
    const int*   eidx =(const int*)  d_in[2];
    const float* eattr=(const float*)d_in[3];
    const float* sW1=(const float*)d_in[4];  const float* sb1=(const float*)d_in[5];
    const float* sW2=(const float*)d_in[6];  const float* sb2=(const float*)d_in[7];
    const float* dW1=(const float*)d_in[8];  const float* db1=(const float*)d_in[9];
    const float* dW2=(const float*)d_in[10]; const float* db2=(const float*)d_in[11];
    const float* eW1=(const float*)d_in[12]; const float* eb1=(const float*)d_in[13];
    const float* eW2=(const float*)d_in[14]; const float* eb2=(const float*)d_in[15];
    const float* gW1=(const float*)d_in[16]; const float* gb1=(const float*)d_in[17];
    const float* gW2=(const float*)d_in[18]; const float* gb2=(const float*)d_in[19];
    const float* oW1=(const float*)d_in[20]; const float* ob1=(const float*)d_in[21];
    const float* oW2=(const float*)d_in[22]; const float* ob2=(const float*)d_in[23];
    float* out=(float*)d_out;

    char* p=(char*)d_ws;
    size_t used=0;
    auto alloc=[&](size_t bytes)->char*{
        char* r=p+used; used += (bytes+255)&~(size_t)255; return r;
    };
    ushort* WT_A=(ushort*)alloc(HID*HID*2);
    ushort* WT_B=(ushort*)alloc(HID*HID*2);
    ushort* WT_E=(ushort*)alloc(HID*HID*2);
    ushort* WT_d=(ushort*)alloc(HID*HID*2);
    ushort* WT_g=(ushort*)alloc(HID*HID*2);
    ushort* WT_o=(ushort*)alloc(HID*HID*2);
    ushort* WT_e1=(ushort*)alloc(HID*32*2);
    ushort* WT_s1=(ushort*)alloc(HID*32*2);
    ushort* WT_d1=(ushort*)alloc(HID*32*2);
    float* bias_A=(float*)alloc(HID*4);
    float* bias_B=(float*)alloc(HID*4);
    ushort* gA=(ushort*)alloc((size_t)N_NODES*HID*2);
    ushort* gB=(ushort*)alloc((size_t)N_NODES*HID*2);
    ushort* g =(ushort*)alloc((size_t)N_EDGES*HID*2);
    ushort* h0=(ushort*)alloc((size_t)N_NODES*HID*2);
    uint* deg      =(uint*)alloc(N_NODES*4);
    uint* row_start=(uint*)alloc(N_NODES*4);
    uint* cursor   =(uint*)alloc(N_NODES*4);
    int* csr_src=(int*)alloc(N_EDGES*4);
    int* csr_eid=(int*)alloc(N_EDGES*4);
    ushort* h1=gA;   // alias: gA/gB dead after edge_encode

    if (used > ws_size) return;  // clean fail if ws too small

    hipMemsetAsync(deg, 0, N_NODES*4, stream);
    hipMemsetAsync(cursor, 0, N_NODES*4, stream);

    combine_weights<<<dim3(HID+1,9),256,0,stream>>>(sW2,sb2,eW2,eb2,gW1,gb1,dW2,gW2,oW1,eW1,eb1,sW1,sb1,dW1,db1,
                                                    WT_A,WT_B,WT_E,WT_d,WT_g,WT_o,WT_e1,WT_s1,WT_d1,bias_A,bias_B);
    node_encode_mfma<<<(N_NODES+63)/64,256,0,stream>>>(sfeat,dfeat,WT_s1,WT_d1,WT_d,db2,WT_A,bias_A,WT_B,bias_B,gA,gB,h0);
    deg_count<<<(N_EDGES+255)/256,256,0,stream>>>(eidx,deg);
    scan_kernel<<<1,1024,0,stream>>>(deg,row_start);
    csr_fill<<<(N_EDGES+255)/256,256,0,stream>>>(eidx,row_start,cursor,csr_src,csr_eid);
    edge_encode_mfma<<<(N_EDGES+127)/128,512,0,stream>>>(eattr,eidx,csr_src,csr_eid,WT_e1,WT_E,WT_g,gb2,gA,gB,g);
    hop_kernel<<<N_NODES/4,256,0,stream>>>(h0,h1,g,csr_src,row_start,deg);
    hop_kernel<<<N_NODES/4,256,0,stream>>>(h1,h0,g,csr_src,row_start,deg);
    decoder_mfma<<<(N_NODES+63)/64,256,0,stream>>>(h0,WT_o,ob1,oW2,ob2,out);
}